// Round 2
// baseline (1978.075 us; speedup 1.0000x reference)
//
#include <hip/hip_runtime.h>
#include <hip/hip_bf16.h>

// DeltaNet block, f32 correctness-first implementation.
// B=2 L=4096 D=1024 H=8 DK=DV=128 KCONV=4 CHUNK=64
#define B_ 2
#define L_ 4096
#define D_ 1024
#define H_ 8
#define DK_ 128
#define NR_ (B_*L_)      // 8192 rows
#define NC_ 64           // chunks per sequence
#define CS_ 64           // chunk size
// ws layout (floats): h, b1(qlin/W), b2(klin/U), b3(vlin/o), q, k, v  (7 x 8388608)
// + qk_buf (1024*4096) + beta (8192*8)  => 251,920,384 bytes total.

__device__ __forceinline__ float sigmf(float x){ return 1.0f/(1.0f+__expf(-x)); }
__device__ __forceinline__ float siluf(float x){ return x/(1.0f+__expf(-x)); }

// ---------- RMSNorm over D ----------
__global__ __launch_bounds__(256) void rmsnorm_kernel(const float* __restrict__ x,
    const float* __restrict__ w, float* __restrict__ h){
  int n = blockIdx.x; int t = threadIdx.x;
  float4 v = ((const float4*)(x + (size_t)n*D_))[t];
  float ss = v.x*v.x + v.y*v.y + v.z*v.z + v.w*v.w;
  #pragma unroll
  for (int m=32;m>0;m>>=1) ss += __shfl_xor(ss, m, 64);
  __shared__ float red[4];
  if ((t&63)==0) red[t>>6] = ss;
  __syncthreads();
  ss = red[0]+red[1]+red[2]+red[3];
  float rs = rsqrtf(ss*(1.0f/D_) + 1e-6f);
  float4 wv = ((const float4*)w)[t];
  float4 o; o.x=v.x*rs*wv.x; o.y=v.y*rs*wv.y; o.z=v.z*rs*wv.z; o.w=v.w*rs*wv.w;
  ((float4*)(h + (size_t)n*D_))[t] = o;
}

// ---------- f32 GEMM: C[M,N] = A[M,K]@B[K,N] (+R), 64x64 tile, 4x4/thread ----------
__global__ __launch_bounds__(256) void gemm_f32(const float* __restrict__ A,
    const float* __restrict__ Bw, const float* __restrict__ R, float* __restrict__ C,
    int M, int N, int K){
  __shared__ float As[16][68];
  __shared__ float Bs[16][68];
  int t = threadIdx.x;
  int tx = t & 15, ty = t >> 4;
  int row0 = blockIdx.y*64, col0 = blockIdx.x*64;
  int ra = t >> 2, ka = (t & 3)*4;
  int kb = t >> 4, cb2 = (t & 15)*4;
  float acc[4][4] = {};
  for (int k0=0;k0<K;k0+=16){
    float4 av = *(const float4*)&A[(size_t)(row0+ra)*K + k0 + ka];
    float4 bv = *(const float4*)&Bw[(size_t)(k0+kb)*N + col0 + cb2];
    As[ka+0][ra]=av.x; As[ka+1][ra]=av.y; As[ka+2][ra]=av.z; As[ka+3][ra]=av.w;
    *(float4*)&Bs[kb][cb2] = bv;
    __syncthreads();
    #pragma unroll
    for (int kk=0;kk<16;kk++){
      float4 a4 = *(const float4*)&As[kk][ty*4];
      float4 b4 = *(const float4*)&Bs[kk][tx*4];
      float aa[4] = {a4.x,a4.y,a4.z,a4.w};
      float bb[4] = {b4.x,b4.y,b4.z,b4.w};
      #pragma unroll
      for (int i=0;i<4;i++){
        #pragma unroll
        for (int j=0;j<4;j++) acc[i][j] += aa[i]*bb[j];
      }
    }
    __syncthreads();
  }
  #pragma unroll
  for (int i=0;i<4;i++){
    #pragma unroll
    for (int j=0;j<4;j++){
      size_t idx = (size_t)(row0+ty*4+i)*N + col0 + tx*4 + j;
      float r = R ? R[idx] : 0.0f;
      C[idx] = acc[i][j] + r;
    }
  }
}

// ---------- beta = sigmoid(h @ Wb[1024,8]) ----------
__global__ __launch_bounds__(256) void beta_kernel(const float* __restrict__ h,
    const float* __restrict__ Wb, float* __restrict__ beta){
  int n = blockIdx.x, t = threadIdx.x;
  const float* hr = h + (size_t)n*D_;
  float p[8] = {};
  for (int kx=t; kx<D_; kx+=256){
    float hv = hr[kx];
    const float* wr = Wb + (size_t)kx*H_;
    #pragma unroll
    for (int j=0;j<8;j++) p[j] += hv*wr[j];
  }
  #pragma unroll
  for (int m=32;m>0;m>>=1){
    #pragma unroll
    for (int j=0;j<8;j++) p[j] += __shfl_xor(p[j], m, 64);
  }
  __shared__ float red[4][8];
  if ((t&63)==0){
    #pragma unroll
    for (int j=0;j<8;j++) red[t>>6][j] = p[j];
  }
  __syncthreads();
  if (t < 8){
    float s = red[0][t]+red[1][t]+red[2][t]+red[3][t];
    beta[(size_t)n*H_ + t] = sigmf(s);
  }
}

// ---------- causal depthwise conv(K=4) + silu ----------
__global__ __launch_bounds__(256) void conv_silu_kernel(const float* __restrict__ in,
    const float* __restrict__ w, float* __restrict__ out){
  size_t idx = (size_t)blockIdx.x*256 + threadIdx.x;
  int c = (int)(idx & (D_-1));
  int n = (int)(idx >> 10);
  int l = n & (L_-1);
  float4 wv = ((const float4*)w)[c];           // w[c][0..3]; w[c][i] multiplies x[l-3+i]
  float acc = wv.w * in[idx];
  if (l >= 1) acc += wv.z * in[idx - D_];
  if (l >= 2) acc += wv.y * in[idx - 2*D_];
  if (l >= 3) acc += wv.x * in[idx - 3*D_];
  out[idx] = siluf(acc);
}

// ---------- second silu + per-head l2norm (+optional q scale) ----------
__global__ __launch_bounds__(256) void silu_l2norm_kernel(float* __restrict__ a, float scale){
  int n = blockIdx.x, t = threadIdx.x;     // thread covers channels 4t..4t+3; head = 32 threads
  float* row = a + (size_t)n*D_;
  float4 v = ((const float4*)row)[t];
  float4 u; u.x=siluf(v.x); u.y=siluf(v.y); u.z=siluf(v.z); u.w=siluf(v.w);
  float ss = u.x*u.x+u.y*u.y+u.z*u.z+u.w*u.w;
  #pragma unroll
  for (int m=16;m>0;m>>=1) ss += __shfl_xor(ss, m, 64);   // reduce within 32-lane head group
  float rs = rsqrtf(ss + 1e-6f) * scale;
  u.x*=rs; u.y*=rs; u.z*=rs; u.w*=rs;
  ((float4*)row)[t] = u;
}

// ---------- chunk-local: A=I+tril(b*kk,-1); w=A^-1(bk); u=A^-1(bv); qk masked ----------
__global__ __launch_bounds__(256) void chunk_local_kernel(
    const float* __restrict__ q, const float* __restrict__ k, const float* __restrict__ v,
    const float* __restrict__ beta, float* __restrict__ w_buf, float* __restrict__ u_buf,
    float* __restrict__ qk_buf){
  int ci = blockIdx.x, bh = blockIdx.y;
  int b = bh >> 3, hh = bh & 7;
  int n0 = b*L_ + ci*CS_;
  int cbase = hh*DK_;
  int cid = bh*NC_ + ci;
  __shared__ float Ks[64][132];
  __shared__ float Als[64*68];
  __shared__ float rowW[144];
  __shared__ float rowU[144];
  __shared__ float bs[64];
  int t = threadIdx.x;
  {
    int r = t >> 2, c0 = (t & 3)*32;
    const float* kr = k + (size_t)(n0+r)*D_ + cbase + c0;
    #pragma unroll
    for (int m=0;m<32;m+=4) *(float4*)&Ks[r][c0+m] = *(const float4*)&kr[m];
  }
  if (t < 64) bs[t] = beta[(size_t)(n0+t)*H_ + hh];
  __syncthreads();
  int ti = t >> 4, tj = t & 15;
  // A[i][j] = b_i * (k_i . k_j) for j<i (strict lower), else 0
  {
    float cc[4][4] = {};
    #pragma unroll 2
    for (int d=0; d<128; d+=4){
      float4 ar[4], br[4];
      #pragma unroll
      for (int r2=0;r2<4;r2++) ar[r2] = *(const float4*)&Ks[ti+16*r2][d];
      #pragma unroll
      for (int s2=0;s2<4;s2++) br[s2] = *(const float4*)&Ks[tj+16*s2][d];
      #pragma unroll
      for (int r2=0;r2<4;r2++){
        #pragma unroll
        for (int s2=0;s2<4;s2++){
          cc[r2][s2] += ar[r2].x*br[s2].x + ar[r2].y*br[s2].y
                      + ar[r2].z*br[s2].z + ar[r2].w*br[s2].w;
        }
      }
    }
    #pragma unroll
    for (int r2=0;r2<4;r2++){
      #pragma unroll
      for (int s2=0;s2<4;s2++){
        int i2 = ti + 16*r2, j2 = tj + 16*s2;
        Als[i2*68 + j2] = (j2 < i2) ? bs[i2]*cc[r2][s2] : 0.0f;
      }
    }
  }
  __syncthreads();
  // forward substitution, unit-lower A: row i held by 4 threads (32 f32 each)
  int i = t >> 2, part = t & 3, ds = part*32, dp = part*36;
  float wreg[32], ureg[32];
  {
    float bi = bs[i];
    const float* vr = v + (size_t)(n0+i)*D_ + cbase + ds;
    #pragma unroll
    for (int m=0;m<32;m++) wreg[m] = bi * Ks[i][ds+m];
    #pragma unroll
    for (int m=0;m<32;m+=4){
      float4 vv = *(const float4*)&vr[m];
      ureg[m+0]=bi*vv.x; ureg[m+1]=bi*vv.y; ureg[m+2]=bi*vv.z; ureg[m+3]=bi*vv.w;
    }
  }
  for (int j=0;j<63;j++){
    if (i == j){
      #pragma unroll
      for (int m=0;m<32;m++){ rowW[dp+m]=wreg[m]; rowU[dp+m]=ureg[m]; }
    }
    __syncthreads();
    if (i > j){
      float aj = Als[i*68 + j];
      #pragma unroll
      for (int m=0;m<32;m++){ wreg[m] -= aj*rowW[dp+m]; ureg[m] -= aj*rowU[dp+m]; }
    }
    __syncthreads();
  }
  {
    float* wd = w_buf + (size_t)cid*(64*128) + (size_t)i*128 + ds;
    float* ud = u_buf + (size_t)cid*(64*128) + (size_t)i*128 + ds;
    #pragma unroll
    for (int m=0;m<32;m+=4){
      float4 f; f.x=wreg[m]; f.y=wreg[m+1]; f.z=wreg[m+2]; f.w=wreg[m+3];
      *(float4*)&wd[m] = f;
      float4 g; g.x=ureg[m]; g.y=ureg[m+1]; g.z=ureg[m+2]; g.w=ureg[m+3];
      *(float4*)&ud[m] = g;
    }
  }
  __syncthreads();
  // masked qk = (q_c k_c^T) * tril(ones)  (q already scaled by DK^-0.5)
  {
    const float* qbase = q + (size_t)n0*D_ + cbase;
    float cc[4][4] = {};
    #pragma unroll 2
    for (int d=0; d<128; d+=4){
      float4 ar[4], br[4];
      #pragma unroll
      for (int r2=0;r2<4;r2++) ar[r2] = *(const float4*)&qbase[(size_t)(ti+16*r2)*D_ + d];
      #pragma unroll
      for (int s2=0;s2<4;s2++) br[s2] = *(const float4*)&Ks[tj+16*s2][d];
      #pragma unroll
      for (int r2=0;r2<4;r2++){
        #pragma unroll
        for (int s2=0;s2<4;s2++){
          cc[r2][s2] += ar[r2].x*br[s2].x + ar[r2].y*br[s2].y
                      + ar[r2].z*br[s2].z + ar[r2].w*br[s2].w;
        }
      }
    }
    float* qkd = qk_buf + (size_t)cid*4096;
    #pragma unroll
    for (int r2=0;r2<4;r2++){
      #pragma unroll
      for (int s2=0;s2<4;s2++){
        int i2 = ti+16*r2, j2 = tj+16*s2;
        qkd[i2*64 + j2] = (j2 <= i2) ? cc[r2][s2] : 0.0f;
      }
    }
  }
}

// ---------- sequential scan over chunks; per-block: one (b,h) x 8 value-cols ----------
__global__ __launch_bounds__(256) void seq_kernel(
    const float* __restrict__ w_buf, const float* __restrict__ u_buf,
    const float* __restrict__ q, const float* __restrict__ k,
    const float* __restrict__ qk_buf, float* __restrict__ o_buf){
  int cg = blockIdx.x;   // 0..15 col group (8 cols)
  int bh = blockIdx.y;   // 0..15
  int b = bh >> 3, hh = bh & 7;
  int cbase = hh*DK_;
  int t = threadIdx.x;
  __shared__ float Wl[64][132];
  __shared__ float S[8][132];
  __shared__ float vn[8][68];
  for (int z=t; z<8*132; z+=256) ((float*)S)[z] = 0.0f;
  __syncthreads();
  int c = t & 7;
  int rg = t >> 3;            // 0..31
  int lr = t >> 2, lc0 = (t & 3)*32;
  for (int ci=0; ci<NC_; ++ci){
    int cid = bh*NC_ + ci;
    int n0 = b*L_ + ci*CS_;
    { // load W
      const float* p = w_buf + (size_t)cid*(64*128) + (size_t)lr*128 + lc0;
      #pragma unroll
      for (int m=0;m<32;m+=4) *(float4*)&Wl[lr][lc0+m] = *(const float4*)&p[m];
    }
    __syncthreads();
    { // v_new = u - w @ S   (cols cg*8+c)
      const float* Ug = u_buf + (size_t)cid*(64*128);
      #pragma unroll
      for (int e=0;e<2;e++){
        int i2 = rg*2+e;
        float acc = 0.0f;
        #pragma unroll 8
        for (int d=0; d<128; d+=4){
          float4 wv = *(const float4*)&Wl[i2][d];
          float4 sv = *(const float4*)&S[c][d];
          acc += wv.x*sv.x + wv.y*sv.y + wv.z*sv.z + wv.w*sv.w;
        }
        vn[c][i2] = Ug[(size_t)i2*128 + cg*8 + c] - acc;
      }
    }
    __syncthreads();
    { // load Q
      const float* p = q + (size_t)(n0+lr)*D_ + cbase + lc0;
      #pragma unroll
      for (int m=0;m<32;m+=4) *(float4*)&Wl[lr][lc0+m] = *(const float4*)&p[m];
    }
    __syncthreads();
    { // o = q@S + qkm@v_new
      const float* qkr = qk_buf + (size_t)cid*4096;
      #pragma unroll
      for (int e=0;e<2;e++){
        int i2 = rg*2+e;
        float acc = 0.0f;
        #pragma unroll 8
        for (int d=0; d<128; d+=4){
          float4 wv = *(const float4*)&Wl[i2][d];
          float4 sv = *(const float4*)&S[c][d];
          acc += wv.x*sv.x + wv.y*sv.y + wv.z*sv.z + wv.w*sv.w;
        }
        const float* qr = qkr + (size_t)i2*64;
        #pragma unroll 8
        for (int j2=0;j2<64;j2+=4){
          float4 a4 = *(const float4*)&qr[j2];
          float4 v4 = *(const float4*)&vn[c][j2];
          acc += a4.x*v4.x + a4.y*v4.y + a4.z*v4.z + a4.w*v4.w;
        }
        o_buf[(size_t)(n0+i2)*D_ + cbase + cg*8 + c] = acc;
      }
    }
    __syncthreads();
    { // load K
      const float* p = k + (size_t)(n0+lr)*D_ + cbase + lc0;
      #pragma unroll
      for (int m=0;m<32;m+=4) *(float4*)&Wl[lr][lc0+m] = *(const float4*)&p[m];
    }
    __syncthreads();
    { // S += k^T @ v_new
      int d0 = (t >> 3)*4;
      float4 sv = *(const float4*)&S[c][d0];
      float s0=sv.x, s1=sv.y, s2=sv.z, s3=sv.w;
      #pragma unroll 8
      for (int i2=0;i2<64;i2++){
        float vv = vn[c][i2];
        float4 kv = *(const float4*)&Wl[i2][d0];
        s0 += kv.x*vv; s1 += kv.y*vv; s2 += kv.z*vv; s3 += kv.w*vv;
      }
      float4 os; os.x=s0; os.y=s1; os.z=s2; os.w=s3;
      *(float4*)&S[c][d0] = os;
    }
    __syncthreads();
  }
}

// ---------- per-head RMSNorm over DV=128 ----------
__global__ __launch_bounds__(256) void head_rmsnorm_kernel(const float* __restrict__ o,
    const float* __restrict__ w, float* __restrict__ out){
  int n = blockIdx.x, t = threadIdx.x;
  float4 v = ((const float4*)(o + (size_t)n*D_))[t];
  float ss = v.x*v.x+v.y*v.y+v.z*v.z+v.w*v.w;
  #pragma unroll
  for (int m=16;m>0;m>>=1) ss += __shfl_xor(ss, m, 64);
  float rs = rsqrtf(ss*(1.0f/DK_) + 1e-6f);
  float4 wv = ((const float4*)w)[t & 31];
  float4 u; u.x=v.x*rs*wv.x; u.y=v.y*rs*wv.y; u.z=v.z*rs*wv.z; u.w=v.w*rs*wv.w;
  ((float4*)(out + (size_t)n*D_))[t] = u;
}

extern "C" void kernel_launch(void* const* d_in, const int* in_sizes, int n_in,
                              void* d_out, int out_size, void* d_ws, size_t ws_size,
                              hipStream_t stream){
  const float* x      = (const float*)d_in[0];
  const float* norm_w = (const float*)d_in[1];
  const float* Wq     = (const float*)d_in[2];
  const float* Wk     = (const float*)d_in[3];
  const float* Wv     = (const float*)d_in[4];
  const float* Wb     = (const float*)d_in[5];
  const float* conv_q = (const float*)d_in[6];
  const float* conv_k = (const float*)d_in[7];
  const float* conv_v = (const float*)d_in[8];
  const float* onw    = (const float*)d_in[9];
  const float* Wo     = (const float*)d_in[10];
  float* out = (float*)d_out;

  const size_t NB = (size_t)NR_*D_;   // 8,388,608 floats
  float* h    = (float*)d_ws;
  float* b1   = h   + NB;   // qlin -> W
  float* b2   = b1  + NB;   // klin -> U
  float* b3   = b2  + NB;   // vlin -> o
  float* qb   = b3  + NB;
  float* kb   = qb  + NB;
  float* vb   = kb  + NB;
  float* qkb  = vb  + NB;                 // 1024*4096
  float* betab= qkb + (size_t)1024*4096;  // 8192*8

  rmsnorm_kernel<<<NR_, 256, 0, stream>>>(x, norm_w, h);
  dim3 gg(D_/64, NR_/64);
  gemm_f32<<<gg, 256, 0, stream>>>(h, Wq, nullptr, b1, NR_, D_, D_);
  gemm_f32<<<gg, 256, 0, stream>>>(h, Wk, nullptr, b2, NR_, D_, D_);
  gemm_f32<<<gg, 256, 0, stream>>>(h, Wv, nullptr, b3, NR_, D_, D_);
  beta_kernel<<<NR_, 256, 0, stream>>>(h, Wb, betab);
  conv_silu_kernel<<<(int)(NB/256), 256, 0, stream>>>(b1, conv_q, qb);
  conv_silu_kernel<<<(int)(NB/256), 256, 0, stream>>>(b2, conv_k, kb);
  conv_silu_kernel<<<(int)(NB/256), 256, 0, stream>>>(b3, conv_v, vb);
  const float qscale = 0.08838834764831845f;  // DK^-0.5
  silu_l2norm_kernel<<<NR_, 256, 0, stream>>>(qb, qscale);
  silu_l2norm_kernel<<<NR_, 256, 0, stream>>>(kb, 1.0f);
  chunk_local_kernel<<<dim3(NC_, 16), 256, 0, stream>>>(qb, kb, vb, betab, b1, b2, qkb);
  seq_kernel<<<dim3(16, 16), 256, 0, stream>>>(b1, b2, qb, kb, qkb, b3);
  head_rmsnorm_kernel<<<NR_, 256, 0, stream>>>(b3, onw, h);
  gemm_f32<<<gg, 256, 0, stream>>>(h, Wo, x, out, NR_, D_, D_);
  (void)in_sizes; (void)n_in; (void)out_size; (void)ws_size;
}

// Round 3
// 1199.350 us; speedup vs baseline: 1.6493x; 1.6493x over previous
//
#include <hip/hip_runtime.h>
#include <hip/hip_bf16.h>

// DeltaNet block. B=2 L=4096 D=1024 H=8 DK=DV=128 KCONV=4 CHUNK=64
// Round 3: bf16 MFMA for the 4 big GEMMs + XCD-swizzled seq_kernel.
#define B_ 2
#define L_ 4096
#define D_ 1024
#define H_ 8
#define DK_ 128
#define NR_ (B_*L_)      // 8192 rows
#define NC_ 64           // chunks per sequence
#define CS_ 64           // chunk size

typedef __attribute__((ext_vector_type(8))) short short8;
typedef __attribute__((ext_vector_type(4))) float f32x4;

__device__ __forceinline__ float sigmf(float x){ return 1.0f/(1.0f+__expf(-x)); }
__device__ __forceinline__ float siluf(float x){ return x/(1.0f+__expf(-x)); }
__device__ __forceinline__ unsigned short f2bf(float f){
  __hip_bfloat16 h = __float2bfloat16(f);
  return *reinterpret_cast<unsigned short*>(&h);
}
__device__ __forceinline__ void gll16(const void* g, void* l){
  __builtin_amdgcn_global_load_lds((const __attribute__((address_space(1))) void*)g,
      (__attribute__((address_space(3))) void*)l, 16, 0, 0);
}

// ---------- RMSNorm over D, dual f32 + bf16 output ----------
__global__ __launch_bounds__(256) void rmsnorm_kernel(const float* __restrict__ x,
    const float* __restrict__ w, float* __restrict__ h, unsigned short* __restrict__ hb){
  int n = blockIdx.x; int t = threadIdx.x;
  float4 v = ((const float4*)(x + (size_t)n*D_))[t];
  float ss = v.x*v.x + v.y*v.y + v.z*v.z + v.w*v.w;
  #pragma unroll
  for (int m=32;m>0;m>>=1) ss += __shfl_xor(ss, m, 64);
  __shared__ float red[4];
  if ((t&63)==0) red[t>>6] = ss;
  __syncthreads();
  ss = red[0]+red[1]+red[2]+red[3];
  float rs = rsqrtf(ss*(1.0f/D_) + 1e-6f);
  float4 wv = ((const float4*)w)[t];
  float4 o; o.x=v.x*rs*wv.x; o.y=v.y*rs*wv.y; o.z=v.z*rs*wv.z; o.w=v.w*rs*wv.w;
  ((float4*)(h + (size_t)n*D_))[t] = o;
  ushort4 ob4; ob4.x=f2bf(o.x); ob4.y=f2bf(o.y); ob4.z=f2bf(o.z); ob4.w=f2bf(o.w);
  ((ushort4*)(hb + (size_t)n*D_))[t] = ob4;
}

// ---------- transpose + f32->bf16: W[1024][1024] -> Wt[n][k] ----------
__global__ __launch_bounds__(256) void transpose_bf16_kernel(const float* __restrict__ W,
    unsigned short* __restrict__ Wt){
  __shared__ float tile[64][65];
  int bi = blockIdx.y, bj = blockIdx.x;
  int tx = threadIdx.x & 63, tg = threadIdx.x >> 6;
  #pragma unroll
  for (int i=0;i<16;i++){
    int r = tg*16 + i;
    tile[r][tx] = W[(size_t)(bi*64 + r)*D_ + bj*64 + tx];
  }
  __syncthreads();
  #pragma unroll
  for (int i=0;i<16;i++){
    int r = tg*16 + i;
    Wt[(size_t)(bj*64 + r)*D_ + bi*64 + tx] = f2bf(tile[tx][r]);
  }
}

// ---------- bf16 MFMA GEMM: C[M,N] f32 = A[M,K]bf16 @ Bt[N,K]bf16^T (+R) ----------
// 128x128 tile, BK=32, 4 waves (2x2), fragment-ordered LDS via global_load_lds.
__global__ __launch_bounds__(256) void gemm_bf16(const unsigned short* __restrict__ A,
    const unsigned short* __restrict__ Bt, const float* __restrict__ R,
    float* __restrict__ C, int N, int K){
  __shared__ __align__(16) unsigned short Al[4096];  // 8 frag-chunks x 64 lanes x 8 bf16
  __shared__ __align__(16) unsigned short Bl[4096];
  int t = threadIdx.x, w = t>>6, l = t&63;
  int wm = w&1, wn = w>>1;
  int row0 = blockIdx.y*128, col0 = blockIdx.x*128;
  int lr = l&15, lk = l>>4;
  // per-lane global gather: chunk fm holds A[row0+16*fm+(l&15)][k0+8*(l>>4) .. +7]
  const unsigned short* ga0 = A  + (size_t)(row0 + w*16     + lr)*K + lk*8;
  const unsigned short* ga1 = A  + (size_t)(row0 + (w+4)*16 + lr)*K + lk*8;
  const unsigned short* gb0 = Bt + (size_t)(col0 + w*16     + lr)*K + lk*8;
  const unsigned short* gb1 = Bt + (size_t)(col0 + (w+4)*16 + lr)*K + lk*8;
  unsigned short* la0 = &Al[(w*64 + l)*8];
  unsigned short* la1 = &Al[((w+4)*64 + l)*8];
  unsigned short* lb0 = &Bl[(w*64 + l)*8];
  unsigned short* lb1 = &Bl[((w+4)*64 + l)*8];
  f32x4 acc[4][4];
  #pragma unroll
  for (int i=0;i<4;i++)
    #pragma unroll
    for (int j=0;j<4;j++) acc[i][j] = (f32x4){0.f,0.f,0.f,0.f};
  for (int k0=0;k0<K;k0+=32){
    gll16(ga0 + k0, la0);
    gll16(ga1 + k0, la1);
    gll16(gb0 + k0, lb0);
    gll16(gb1 + k0, lb1);
    __syncthreads();            // compiler emits vmcnt(0) drain here
    short8 af[4], bfr[4];
    #pragma unroll
    for (int i=0;i<4;i++) af[i]  = *(const short8*)&Al[((wm*4+i)*64 + l)*8];
    #pragma unroll
    for (int j=0;j<4;j++) bfr[j] = *(const short8*)&Bl[((wn*4+j)*64 + l)*8];
    #pragma unroll
    for (int i=0;i<4;i++)
      #pragma unroll
      for (int j=0;j<4;j++)
        acc[i][j] = __builtin_amdgcn_mfma_f32_16x16x32_bf16(af[i], bfr[j], acc[i][j], 0,0,0);
    __syncthreads();
  }
  // C/D layout: col = lane&15, row = (lane>>4)*4 + reg  [m89-verified]
  int orow = row0 + wm*64 + (l>>4)*4;
  int ocol = col0 + wn*64 + (l&15);
  #pragma unroll
  for (int i=0;i<4;i++){
    #pragma unroll
    for (int j=0;j<4;j++){
      #pragma unroll
      for (int r=0;r<4;r++){
        size_t idx = (size_t)(orow + i*16 + r)*N + ocol + j*16;
        float res = R ? R[idx] : 0.0f;
        C[idx] = acc[i][j][r] + res;
      }
    }
  }
}

// ---------- beta = sigmoid(h @ Wb[1024,8]) ----------
__global__ __launch_bounds__(256) void beta_kernel(const float* __restrict__ h,
    const float* __restrict__ Wb, float* __restrict__ beta){
  int n = blockIdx.x, t = threadIdx.x;
  const float* hr = h + (size_t)n*D_;
  float p[8] = {};
  for (int kx=t; kx<D_; kx+=256){
    float hv = hr[kx];
    const float* wr = Wb + (size_t)kx*H_;
    #pragma unroll
    for (int j=0;j<8;j++) p[j] += hv*wr[j];
  }
  #pragma unroll
  for (int m=32;m>0;m>>=1){
    #pragma unroll
    for (int j=0;j<8;j++) p[j] += __shfl_xor(p[j], m, 64);
  }
  __shared__ float red[4][8];
  if ((t&63)==0){
    #pragma unroll
    for (int j=0;j<8;j++) red[t>>6][j] = p[j];
  }
  __syncthreads();
  if (t < 8){
    float s = red[0][t]+red[1][t]+red[2][t]+red[3][t];
    beta[(size_t)n*H_ + t] = sigmf(s);
  }
}

// ---------- causal depthwise conv(K=4) + silu ----------
__global__ __launch_bounds__(256) void conv_silu_kernel(const float* __restrict__ in,
    const float* __restrict__ w, float* __restrict__ out){
  size_t idx = (size_t)blockIdx.x*256 + threadIdx.x;
  int c = (int)(idx & (D_-1));
  int n = (int)(idx >> 10);
  int l = n & (L_-1);
  float4 wv = ((const float4*)w)[c];
  float acc = wv.w * in[idx];
  if (l >= 1) acc += wv.z * in[idx - D_];
  if (l >= 2) acc += wv.y * in[idx - 2*D_];
  if (l >= 3) acc += wv.x * in[idx - 3*D_];
  out[idx] = siluf(acc);
}

// ---------- second silu + per-head l2norm (+optional q scale) ----------
__global__ __launch_bounds__(256) void silu_l2norm_kernel(float* __restrict__ a, float scale){
  int n = blockIdx.x, t = threadIdx.x;
  float* row = a + (size_t)n*D_;
  float4 v = ((const float4*)row)[t];
  float4 u; u.x=siluf(v.x); u.y=siluf(v.y); u.z=siluf(v.z); u.w=siluf(v.w);
  float ss = u.x*u.x+u.y*u.y+u.z*u.z+u.w*u.w;
  #pragma unroll
  for (int m=16;m>0;m>>=1) ss += __shfl_xor(ss, m, 64);
  float rs = rsqrtf(ss + 1e-6f) * scale;
  u.x*=rs; u.y*=rs; u.z*=rs; u.w*=rs;
  ((float4*)row)[t] = u;
}

// ---------- chunk-local: A=I+tril(b*kk,-1); w=A^-1(bk); u=A^-1(bv); qk masked ----------
__global__ __launch_bounds__(256) void chunk_local_kernel(
    const float* __restrict__ q, const float* __restrict__ k, const float* __restrict__ v,
    const float* __restrict__ beta, float* __restrict__ w_buf, float* __restrict__ u_buf,
    float* __restrict__ qk_buf){
  int ci = blockIdx.x, bh = blockIdx.y;
  int b = bh >> 3, hh = bh & 7;
  int n0 = b*L_ + ci*CS_;
  int cbase = hh*DK_;
  int cid = bh*NC_ + ci;
  __shared__ float Ks[64][132];
  __shared__ float Als[64*68];
  __shared__ float rowW[144];
  __shared__ float rowU[144];
  __shared__ float bs[64];
  int t = threadIdx.x;
  {
    int r = t >> 2, c0 = (t & 3)*32;
    const float* kr = k + (size_t)(n0+r)*D_ + cbase + c0;
    #pragma unroll
    for (int m=0;m<32;m+=4) *(float4*)&Ks[r][c0+m] = *(const float4*)&kr[m];
  }
  if (t < 64) bs[t] = beta[(size_t)(n0+t)*H_ + hh];
  __syncthreads();
  int ti = t >> 4, tj = t & 15;
  {
    float cc[4][4] = {};
    #pragma unroll 2
    for (int d=0; d<128; d+=4){
      float4 ar[4], br[4];
      #pragma unroll
      for (int r2=0;r2<4;r2++) ar[r2] = *(const float4*)&Ks[ti+16*r2][d];
      #pragma unroll
      for (int s2=0;s2<4;s2++) br[s2] = *(const float4*)&Ks[tj+16*s2][d];
      #pragma unroll
      for (int r2=0;r2<4;r2++){
        #pragma unroll
        for (int s2=0;s2<4;s2++){
          cc[r2][s2] += ar[r2].x*br[s2].x + ar[r2].y*br[s2].y
                      + ar[r2].z*br[s2].z + ar[r2].w*br[s2].w;
        }
      }
    }
    #pragma unroll
    for (int r2=0;r2<4;r2++){
      #pragma unroll
      for (int s2=0;s2<4;s2++){
        int i2 = ti + 16*r2, j2 = tj + 16*s2;
        Als[i2*68 + j2] = (j2 < i2) ? bs[i2]*cc[r2][s2] : 0.0f;
      }
    }
  }
  __syncthreads();
  int i = t >> 2, part = t & 3, ds = part*32, dp = part*36;
  float wreg[32], ureg[32];
  {
    float bi = bs[i];
    const float* vr = v + (size_t)(n0+i)*D_ + cbase + ds;
    #pragma unroll
    for (int m=0;m<32;m++) wreg[m] = bi * Ks[i][ds+m];
    #pragma unroll
    for (int m=0;m<32;m+=4){
      float4 vv = *(const float4*)&vr[m];
      ureg[m+0]=bi*vv.x; ureg[m+1]=bi*vv.y; ureg[m+2]=bi*vv.z; ureg[m+3]=bi*vv.w;
    }
  }
  for (int j=0;j<63;j++){
    if (i == j){
      #pragma unroll
      for (int m=0;m<32;m++){ rowW[dp+m]=wreg[m]; rowU[dp+m]=ureg[m]; }
    }
    __syncthreads();
    if (i > j){
      float aj = Als[i*68 + j];
      #pragma unroll
      for (int m=0;m<32;m++){ wreg[m] -= aj*rowW[dp+m]; ureg[m] -= aj*rowU[dp+m]; }
    }
    __syncthreads();
  }
  {
    float* wd = w_buf + (size_t)cid*(64*128) + (size_t)i*128 + ds;
    float* ud = u_buf + (size_t)cid*(64*128) + (size_t)i*128 + ds;
    #pragma unroll
    for (int m=0;m<32;m+=4){
      float4 f; f.x=wreg[m]; f.y=wreg[m+1]; f.z=wreg[m+2]; f.w=wreg[m+3];
      *(float4*)&wd[m] = f;
      float4 g; g.x=ureg[m]; g.y=ureg[m+1]; g.z=ureg[m+2]; g.w=ureg[m+3];
      *(float4*)&ud[m] = g;
    }
  }
  __syncthreads();
  {
    const float* qbase = q + (size_t)n0*D_ + cbase;
    float cc[4][4] = {};
    #pragma unroll 2
    for (int d=0; d<128; d+=4){
      float4 ar[4], br[4];
      #pragma unroll
      for (int r2=0;r2<4;r2++) ar[r2] = *(const float4*)&qbase[(size_t)(ti+16*r2)*D_ + d];
      #pragma unroll
      for (int s2=0;s2<4;s2++) br[s2] = *(const float4*)&Ks[tj+16*s2][d];
      #pragma unroll
      for (int r2=0;r2<4;r2++){
        #pragma unroll
        for (int s2=0;s2<4;s2++){
          cc[r2][s2] += ar[r2].x*br[s2].x + ar[r2].y*br[s2].y
                      + ar[r2].z*br[s2].z + ar[r2].w*br[s2].w;
        }
      }
    }
    float* qkd = qk_buf + (size_t)cid*4096;
    #pragma unroll
    for (int r2=0;r2<4;r2++){
      #pragma unroll
      for (int s2=0;s2<4;s2++){
        int i2 = ti+16*r2, j2 = tj+16*s2;
        qkd[i2*64 + j2] = (j2 <= i2) ? cc[r2][s2] : 0.0f;
      }
    }
  }
}

// ---------- sequential scan; XCD-swizzled: all 16 col-groups of one (b,h) on one XCD ----------
__global__ __launch_bounds__(256) void seq_kernel(
    const float* __restrict__ w_buf, const float* __restrict__ u_buf,
    const float* __restrict__ q, const float* __restrict__ k,
    const float* __restrict__ qk_buf, float* __restrict__ o_buf){
  // blockIdx.x = xcd + 8*(cg + 16*(bh>>3)), xcd = bh&7  => same-bh blocks share an XCD L2
  int bid = blockIdx.x;
  int xcd = bid & 7, sub = bid >> 3;
  int cg = sub & 15;
  int bh = xcd + 8*(sub >> 4);
  int b = bh >> 3, hh = bh & 7;
  int cbase = hh*DK_;
  int t = threadIdx.x;
  __shared__ float Wl[64][132];
  __shared__ float S[8][132];
  __shared__ float vn[8][68];
  for (int z=t; z<8*132; z+=256) ((float*)S)[z] = 0.0f;
  __syncthreads();
  int c = t & 7;
  int rg = t >> 3;
  int lr = t >> 2, lc0 = (t & 3)*32;
  for (int ci=0; ci<NC_; ++ci){
    int cid = bh*NC_ + ci;
    int n0 = b*L_ + ci*CS_;
    { // load W
      const float* p = w_buf + (size_t)cid*(64*128) + (size_t)lr*128 + lc0;
      #pragma unroll
      for (int m=0;m<32;m+=4) *(float4*)&Wl[lr][lc0+m] = *(const float4*)&p[m];
    }
    __syncthreads();
    { // v_new = u - w @ S
      const float* Ug = u_buf + (size_t)cid*(64*128);
      #pragma unroll
      for (int e=0;e<2;e++){
        int i2 = rg*2+e;
        float acc = 0.0f;
        #pragma unroll 8
        for (int d=0; d<128; d+=4){
          float4 wv = *(const float4*)&Wl[i2][d];
          float4 sv = *(const float4*)&S[c][d];
          acc += wv.x*sv.x + wv.y*sv.y + wv.z*sv.z + wv.w*sv.w;
        }
        vn[c][i2] = Ug[(size_t)i2*128 + cg*8 + c] - acc;
      }
    }
    __syncthreads();
    { // load Q
      const float* p = q + (size_t)(n0+lr)*D_ + cbase + lc0;
      #pragma unroll
      for (int m=0;m<32;m+=4) *(float4*)&Wl[lr][lc0+m] = *(const float4*)&p[m];
    }
    __syncthreads();
    { // o = q@S + qkm@v_new
      const float* qkr = qk_buf + (size_t)cid*4096;
      #pragma unroll
      for (int e=0;e<2;e++){
        int i2 = rg*2+e;
        float acc = 0.0f;
        #pragma unroll 8
        for (int d=0; d<128; d+=4){
          float4 wv = *(const float4*)&Wl[i2][d];
          float4 sv = *(const float4*)&S[c][d];
          acc += wv.x*sv.x + wv.y*sv.y + wv.z*sv.z + wv.w*sv.w;
        }
        const float* qr = qkr + (size_t)i2*64;
        #pragma unroll 8
        for (int j2=0;j2<64;j2+=4){
          float4 a4 = *(const float4*)&qr[j2];
          float4 v4 = *(const float4*)&vn[c][j2];
          acc += a4.x*v4.x + a4.y*v4.y + a4.z*v4.z + a4.w*v4.w;
        }
        o_buf[(size_t)(n0+i2)*D_ + cbase + cg*8 + c] = acc;
      }
    }
    __syncthreads();
    { // load K
      const float* p = k + (size_t)(n0+lr)*D_ + cbase + lc0;
      #pragma unroll
      for (int m=0;m<32;m+=4) *(float4*)&Wl[lr][lc0+m] = *(const float4*)&p[m];
    }
    __syncthreads();
    { // S += k^T @ v_new
      int d0 = (t >> 3)*4;
      float4 sv = *(const float4*)&S[c][d0];
      float s0=sv.x, s1=sv.y, s2=sv.z, s3=sv.w;
      #pragma unroll 8
      for (int i2=0;i2<64;i2++){
        float vv = vn[c][i2];
        float4 kv = *(const float4*)&Wl[i2][d0];
        s0 += kv.x*vv; s1 += kv.y*vv; s2 += kv.z*vv; s3 += kv.w*vv;
      }
      float4 os; os.x=s0; os.y=s1; os.z=s2; os.w=s3;
      *(float4*)&S[c][d0] = os;
    }
    __syncthreads();
  }
}

// ---------- per-head RMSNorm over DV=128, bf16 out ----------
__global__ __launch_bounds__(256) void head_rmsnorm_kernel(const float* __restrict__ o,
    const float* __restrict__ w, unsigned short* __restrict__ out){
  int n = blockIdx.x, t = threadIdx.x;
  float4 v = ((const float4*)(o + (size_t)n*D_))[t];
  float ss = v.x*v.x+v.y*v.y+v.z*v.z+v.w*v.w;
  #pragma unroll
  for (int m=16;m>0;m>>=1) ss += __shfl_xor(ss, m, 64);
  float rs = rsqrtf(ss*(1.0f/DK_) + 1e-6f);
  float4 wv = ((const float4*)w)[t & 31];
  float4 u; u.x=v.x*rs*wv.x; u.y=v.y*rs*wv.y; u.z=v.z*rs*wv.z; u.w=v.w*rs*wv.w;
  ushort4 r4; r4.x=f2bf(u.x); r4.y=f2bf(u.y); r4.z=f2bf(u.z); r4.w=f2bf(u.w);
  ((ushort4*)(out + (size_t)n*D_))[t] = r4;
}

extern "C" void kernel_launch(void* const* d_in, const int* in_sizes, int n_in,
                              void* d_out, int out_size, void* d_ws, size_t ws_size,
                              hipStream_t stream){
  const float* x      = (const float*)d_in[0];
  const float* norm_w = (const float*)d_in[1];
  const float* Wq     = (const float*)d_in[2];
  const float* Wk     = (const float*)d_in[3];
  const float* Wv     = (const float*)d_in[4];
  const float* Wb     = (const float*)d_in[5];
  const float* conv_q = (const float*)d_in[6];
  const float* conv_k = (const float*)d_in[7];
  const float* conv_v = (const float*)d_in[8];
  const float* onw    = (const float*)d_in[9];
  const float* Wo     = (const float*)d_in[10];
  float* out = (float*)d_out;

  const size_t NB = (size_t)NR_*D_;           // 8,388,608 floats
  float* ws   = (float*)d_ws;
  float* h    = ws;            // f32 h; later reused as ob (bf16)
  float* b1   = ws + NB;       // qlin -> W
  float* b2   = ws + 2*NB;     // klin -> U
  float* b3   = ws + 3*NB;     // vlin -> o
  float* qb   = ws + 4*NB;     // hb (bf16) aliases here until conv_q runs
  float* kb   = ws + 5*NB;
  float* vb   = ws + 6*NB;
  float* qkb  = ws + 7*NB;                    // 4M floats
  float* betab= qkb + (size_t)1024*4096;      // 64K floats
  unsigned short* wtq = (unsigned short*)(betab + 65536);
  unsigned short* wtk = wtq + (size_t)D_*D_;
  unsigned short* wtv = wtk + (size_t)D_*D_;
  unsigned short* wto = wtv + (size_t)D_*D_;
  unsigned short* hb  = (unsigned short*)qb;  // dead before conv_q writes qb
  unsigned short* obb = (unsigned short*)h;   // dead after beta + QKV gemms

  rmsnorm_kernel<<<NR_, 256, 0, stream>>>(x, norm_w, h, hb);
  dim3 tg(16,16);
  transpose_bf16_kernel<<<tg, 256, 0, stream>>>(Wq, wtq);
  transpose_bf16_kernel<<<tg, 256, 0, stream>>>(Wk, wtk);
  transpose_bf16_kernel<<<tg, 256, 0, stream>>>(Wv, wtv);
  transpose_bf16_kernel<<<tg, 256, 0, stream>>>(Wo, wto);
  dim3 gg(D_/128, NR_/128);   // (8, 64)
  gemm_bf16<<<gg, 256, 0, stream>>>(hb, wtq, nullptr, b1, D_, D_);
  gemm_bf16<<<gg, 256, 0, stream>>>(hb, wtk, nullptr, b2, D_, D_);
  gemm_bf16<<<gg, 256, 0, stream>>>(hb, wtv, nullptr, b3, D_, D_);
  beta_kernel<<<NR_, 256, 0, stream>>>(h, Wb, betab);
  conv_silu_kernel<<<(int)(NB/256), 256, 0, stream>>>(b1, conv_q, qb);
  conv_silu_kernel<<<(int)(NB/256), 256, 0, stream>>>(b2, conv_k, kb);
  conv_silu_kernel<<<(int)(NB/256), 256, 0, stream>>>(b3, conv_v, vb);
  const float qscale = 0.08838834764831845f;  // DK^-0.5
  silu_l2norm_kernel<<<NR_, 256, 0, stream>>>(qb, qscale);
  silu_l2norm_kernel<<<NR_, 256, 0, stream>>>(kb, 1.0f);
  chunk_local_kernel<<<dim3(NC_, 16), 256, 0, stream>>>(qb, kb, vb, betab, b1, b2, qkb);
  seq_kernel<<<256, 256, 0, stream>>>(b1, b2, qb, kb, qkb, b3);
  head_rmsnorm_kernel<<<NR_, 256, 0, stream>>>(b3, onw, obb);
  gemm_bf16<<<gg, 256, 0, stream>>>(obb, wto, x, out, D_, D_);
  (void)in_sizes; (void)n_in; (void)out_size; (void)ws_size;
}

// Round 5
// 777.300 us; speedup vs baseline: 2.5448x; 1.5430x over previous
//
#include <hip/hip_runtime.h>
#include <hip/hip_bf16.h>

// DeltaNet block. B=2 L=4096 D=1024 H=8 DK=DV=128 KCONV=4 CHUNK=64
// Round 4: MFMA-based seq scan (v_new/o/S-update as 16x16x32 bf16 MFMA),
// chunk_local emits bf16 (-w), K^T, qk; q gets a bf16 copy.
#define B_ 2
#define L_ 4096
#define D_ 1024
#define H_ 8
#define DK_ 128
#define NR_ (B_*L_)      // 8192 rows
#define NC_ 64           // chunks per sequence
#define CS_ 64           // chunk size

typedef __attribute__((ext_vector_type(8))) short short8;
typedef __attribute__((ext_vector_type(4))) float f32x4;

__device__ __forceinline__ float sigmf(float x){ return 1.0f/(1.0f+__expf(-x)); }
__device__ __forceinline__ float siluf(float x){ return x/(1.0f+__expf(-x)); }
__device__ __forceinline__ unsigned short f2bf(float f){
  __hip_bfloat16 h = __float2bfloat16(f);
  return *reinterpret_cast<unsigned short*>(&h);
}
__device__ __forceinline__ void gll16(const void* g, void* l){
  __builtin_amdgcn_global_load_lds((const __attribute__((address_space(1))) void*)g,
      (__attribute__((address_space(3))) void*)l, 16, 0, 0);
}

// ---------- RMSNorm over D, dual f32 + bf16 output ----------
__global__ __launch_bounds__(256) void rmsnorm_kernel(const float* __restrict__ x,
    const float* __restrict__ w, float* __restrict__ h, unsigned short* __restrict__ hb){
  int n = blockIdx.x; int t = threadIdx.x;
  float4 v = ((const float4*)(x + (size_t)n*D_))[t];
  float ss = v.x*v.x + v.y*v.y + v.z*v.z + v.w*v.w;
  #pragma unroll
  for (int m=32;m>0;m>>=1) ss += __shfl_xor(ss, m, 64);
  __shared__ float red[4];
  if ((t&63)==0) red[t>>6] = ss;
  __syncthreads();
  ss = red[0]+red[1]+red[2]+red[3];
  float rs = rsqrtf(ss*(1.0f/D_) + 1e-6f);
  float4 wv = ((const float4*)w)[t];
  float4 o; o.x=v.x*rs*wv.x; o.y=v.y*rs*wv.y; o.z=v.z*rs*wv.z; o.w=v.w*rs*wv.w;
  ((float4*)(h + (size_t)n*D_))[t] = o;
  ushort4 ob4; ob4.x=f2bf(o.x); ob4.y=f2bf(o.y); ob4.z=f2bf(o.z); ob4.w=f2bf(o.w);
  ((ushort4*)(hb + (size_t)n*D_))[t] = ob4;
}

// ---------- transpose + f32->bf16: W[1024][1024] -> Wt[n][k] ----------
__global__ __launch_bounds__(256) void transpose_bf16_kernel(const float* __restrict__ W,
    unsigned short* __restrict__ Wt){
  __shared__ float tile[64][65];
  int bi = blockIdx.y, bj = blockIdx.x;
  int tx = threadIdx.x & 63, tg = threadIdx.x >> 6;
  #pragma unroll
  for (int i=0;i<16;i++){
    int r = tg*16 + i;
    tile[r][tx] = W[(size_t)(bi*64 + r)*D_ + bj*64 + tx];
  }
  __syncthreads();
  #pragma unroll
  for (int i=0;i<16;i++){
    int r = tg*16 + i;
    Wt[(size_t)(bj*64 + r)*D_ + bi*64 + tx] = f2bf(tile[tx][r]);
  }
}

// ---------- bf16 MFMA GEMM: C[M,N] f32 = A[M,K]bf16 @ Bt[N,K]bf16^T (+R) ----------
__global__ __launch_bounds__(256) void gemm_bf16(const unsigned short* __restrict__ A,
    const unsigned short* __restrict__ Bt, const float* __restrict__ R,
    float* __restrict__ C, int N, int K){
  __shared__ __align__(16) unsigned short Al[4096];
  __shared__ __align__(16) unsigned short Bl[4096];
  int t = threadIdx.x, w = t>>6, l = t&63;
  int wm = w&1, wn = w>>1;
  int row0 = blockIdx.y*128, col0 = blockIdx.x*128;
  int lr = l&15, lk = l>>4;
  const unsigned short* ga0 = A  + (size_t)(row0 + w*16     + lr)*K + lk*8;
  const unsigned short* ga1 = A  + (size_t)(row0 + (w+4)*16 + lr)*K + lk*8;
  const unsigned short* gb0 = Bt + (size_t)(col0 + w*16     + lr)*K + lk*8;
  const unsigned short* gb1 = Bt + (size_t)(col0 + (w+4)*16 + lr)*K + lk*8;
  unsigned short* la0 = &Al[(w*64 + l)*8];
  unsigned short* la1 = &Al[((w+4)*64 + l)*8];
  unsigned short* lb0 = &Bl[(w*64 + l)*8];
  unsigned short* lb1 = &Bl[((w+4)*64 + l)*8];
  f32x4 acc[4][4];
  #pragma unroll
  for (int i=0;i<4;i++)
    #pragma unroll
    for (int j=0;j<4;j++) acc[i][j] = (f32x4){0.f,0.f,0.f,0.f};
  for (int k0=0;k0<K;k0+=32){
    gll16(ga0 + k0, la0);
    gll16(ga1 + k0, la1);
    gll16(gb0 + k0, lb0);
    gll16(gb1 + k0, lb1);
    __syncthreads();
    short8 af[4], bfr[4];
    #pragma unroll
    for (int i=0;i<4;i++) af[i]  = *(const short8*)&Al[((wm*4+i)*64 + l)*8];
    #pragma unroll
    for (int j=0;j<4;j++) bfr[j] = *(const short8*)&Bl[((wn*4+j)*64 + l)*8];
    #pragma unroll
    for (int i=0;i<4;i++)
      #pragma unroll
      for (int j=0;j<4;j++)
        acc[i][j] = __builtin_amdgcn_mfma_f32_16x16x32_bf16(af[i], bfr[j], acc[i][j], 0,0,0);
    __syncthreads();
  }
  int orow = row0 + wm*64 + (l>>4)*4;
  int ocol = col0 + wn*64 + (l&15);
  #pragma unroll
  for (int i=0;i<4;i++){
    #pragma unroll
    for (int j=0;j<4;j++){
      #pragma unroll
      for (int r=0;r<4;r++){
        size_t idx = (size_t)(orow + i*16 + r)*N + ocol + j*16;
        float res = R ? R[idx] : 0.0f;
        C[idx] = acc[i][j][r] + res;
      }
    }
  }
}

// ---------- beta = sigmoid(h @ Wb[1024,8]) ----------
__global__ __launch_bounds__(256) void beta_kernel(const float* __restrict__ h,
    const float* __restrict__ Wb, float* __restrict__ beta){
  int n = blockIdx.x, t = threadIdx.x;
  const float* hr = h + (size_t)n*D_;
  float p[8] = {};
  for (int kx=t; kx<D_; kx+=256){
    float hv = hr[kx];
    const float* wr = Wb + (size_t)kx*H_;
    #pragma unroll
    for (int j=0;j<8;j++) p[j] += hv*wr[j];
  }
  #pragma unroll
  for (int m=32;m>0;m>>=1){
    #pragma unroll
    for (int j=0;j<8;j++) p[j] += __shfl_xor(p[j], m, 64);
  }
  __shared__ float red[4][8];
  if ((t&63)==0){
    #pragma unroll
    for (int j=0;j<8;j++) red[t>>6][j] = p[j];
  }
  __syncthreads();
  if (t < 8){
    float s = red[0][t]+red[1][t]+red[2][t]+red[3][t];
    beta[(size_t)n*H_ + t] = sigmf(s);
  }
}

// ---------- causal depthwise conv(K=4) + silu ----------
__global__ __launch_bounds__(256) void conv_silu_kernel(const float* __restrict__ in,
    const float* __restrict__ w, float* __restrict__ out){
  size_t idx = (size_t)blockIdx.x*256 + threadIdx.x;
  int c = (int)(idx & (D_-1));
  int n = (int)(idx >> 10);
  int l = n & (L_-1);
  float4 wv = ((const float4*)w)[c];
  float acc = wv.w * in[idx];
  if (l >= 1) acc += wv.z * in[idx - D_];
  if (l >= 2) acc += wv.y * in[idx - 2*D_];
  if (l >= 3) acc += wv.x * in[idx - 3*D_];
  out[idx] = siluf(acc);
}

// ---------- second silu + per-head l2norm (+optional q scale, optional bf16 copy) ----------
__global__ __launch_bounds__(256) void silu_l2norm_kernel(float* __restrict__ a, float scale,
    unsigned short* __restrict__ ob){
  int n = blockIdx.x, t = threadIdx.x;
  float* row = a + (size_t)n*D_;
  float4 v = ((const float4*)row)[t];
  float4 u; u.x=siluf(v.x); u.y=siluf(v.y); u.z=siluf(v.z); u.w=siluf(v.w);
  float ss = u.x*u.x+u.y*u.y+u.z*u.z+u.w*u.w;
  #pragma unroll
  for (int m=16;m>0;m>>=1) ss += __shfl_xor(ss, m, 64);
  float rs = rsqrtf(ss + 1e-6f) * scale;
  u.x*=rs; u.y*=rs; u.z*=rs; u.w*=rs;
  ((float4*)row)[t] = u;
  if (ob){
    ushort4 r4; r4.x=f2bf(u.x); r4.y=f2bf(u.y); r4.z=f2bf(u.z); r4.w=f2bf(u.w);
    ((ushort4*)(ob + (size_t)n*D_))[t] = r4;
  }
}

// ---------- chunk-local: w=-A^-1(bk) [bf16], u=A^-1(bv) [f32], qk masked [bf16], kt=K^T [bf16] ----------
__global__ __launch_bounds__(256) void chunk_local_kernel(
    const float* __restrict__ q, const float* __restrict__ k, const float* __restrict__ v,
    const float* __restrict__ beta, unsigned short* __restrict__ wneg_buf,
    float* __restrict__ u_buf, unsigned short* __restrict__ qk_buf,
    unsigned short* __restrict__ kt_buf){
  int ci = blockIdx.x, bh = blockIdx.y;
  int b = bh >> 3, hh = bh & 7;
  int n0 = b*L_ + ci*CS_;
  int cbase = hh*DK_;
  int cid = bh*NC_ + ci;
  __shared__ float Ks[64][132];
  __shared__ float Als[64*68];
  __shared__ float rowW[144];
  __shared__ float rowU[144];
  __shared__ float bs[64];
  int t = threadIdx.x;
  {
    int r = t >> 2, c0 = (t & 3)*32;
    const float* kr = k + (size_t)(n0+r)*D_ + cbase + c0;
    #pragma unroll
    for (int m=0;m<32;m+=4) *(float4*)&Ks[r][c0+m] = *(const float4*)&kr[m];
  }
  if (t < 64) bs[t] = beta[(size_t)(n0+t)*H_ + hh];
  __syncthreads();
  int ti = t >> 4, tj = t & 15;
  {
    float cc[4][4] = {};
    #pragma unroll 2
    for (int d=0; d<128; d+=4){
      float4 ar[4], br[4];
      #pragma unroll
      for (int r2=0;r2<4;r2++) ar[r2] = *(const float4*)&Ks[ti+16*r2][d];
      #pragma unroll
      for (int s2=0;s2<4;s2++) br[s2] = *(const float4*)&Ks[tj+16*s2][d];
      #pragma unroll
      for (int r2=0;r2<4;r2++){
        #pragma unroll
        for (int s2=0;s2<4;s2++){
          cc[r2][s2] += ar[r2].x*br[s2].x + ar[r2].y*br[s2].y
                      + ar[r2].z*br[s2].z + ar[r2].w*br[s2].w;
        }
      }
    }
    #pragma unroll
    for (int r2=0;r2<4;r2++){
      #pragma unroll
      for (int s2=0;s2<4;s2++){
        int i2 = ti + 16*r2, j2 = tj + 16*s2;
        Als[i2*68 + j2] = (j2 < i2) ? bs[i2]*cc[r2][s2] : 0.0f;
      }
    }
  }
  __syncthreads();
  int i = t >> 2, part = t & 3, ds = part*32, dp = part*36;
  float wreg[32], ureg[32];
  {
    float bi = bs[i];
    const float* vr = v + (size_t)(n0+i)*D_ + cbase + ds;
    #pragma unroll
    for (int m=0;m<32;m++) wreg[m] = bi * Ks[i][ds+m];
    #pragma unroll
    for (int m=0;m<32;m+=4){
      float4 vv = *(const float4*)&vr[m];
      ureg[m+0]=bi*vv.x; ureg[m+1]=bi*vv.y; ureg[m+2]=bi*vv.z; ureg[m+3]=bi*vv.w;
    }
  }
  for (int j=0;j<63;j++){
    if (i == j){
      #pragma unroll
      for (int m=0;m<32;m++){ rowW[dp+m]=wreg[m]; rowU[dp+m]=ureg[m]; }
    }
    __syncthreads();
    if (i > j){
      float aj = Als[i*68 + j];
      #pragma unroll
      for (int m=0;m<32;m++){ wreg[m] -= aj*rowW[dp+m]; ureg[m] -= aj*rowU[dp+m]; }
    }
    __syncthreads();
  }
  {
    unsigned short* wd = wneg_buf + (size_t)cid*(64*128) + (size_t)i*128 + ds;
    float* ud = u_buf + (size_t)cid*(64*128) + (size_t)i*128 + ds;
    #pragma unroll
    for (int m=0;m<32;m+=4){
      ushort4 f; f.x=f2bf(-wreg[m]); f.y=f2bf(-wreg[m+1]); f.z=f2bf(-wreg[m+2]); f.w=f2bf(-wreg[m+3]);
      *(ushort4*)&wd[m] = f;
      float4 g; g.x=ureg[m]; g.y=ureg[m+1]; g.z=ureg[m+2]; g.w=ureg[m+3];
      *(float4*)&ud[m] = g;
    }
  }
  __syncthreads();
  {
    const float* qbase = q + (size_t)n0*D_ + cbase;
    float cc[4][4] = {};
    #pragma unroll 2
    for (int d=0; d<128; d+=4){
      float4 ar[4], br[4];
      #pragma unroll
      for (int r2=0;r2<4;r2++) ar[r2] = *(const float4*)&qbase[(size_t)(ti+16*r2)*D_ + d];
      #pragma unroll
      for (int s2=0;s2<4;s2++) br[s2] = *(const float4*)&Ks[tj+16*s2][d];
      #pragma unroll
      for (int r2=0;r2<4;r2++){
        #pragma unroll
        for (int s2=0;s2<4;s2++){
          cc[r2][s2] += ar[r2].x*br[s2].x + ar[r2].y*br[s2].y
                      + ar[r2].z*br[s2].z + ar[r2].w*br[s2].w;
        }
      }
    }
    unsigned short* qkd = qk_buf + (size_t)cid*4096;
    #pragma unroll
    for (int r2=0;r2<4;r2++){
      #pragma unroll
      for (int s2=0;s2<4;s2++){
        int i2 = ti+16*r2, j2 = tj+16*s2;
        qkd[i2*64 + j2] = (j2 <= i2) ? f2bf(cc[r2][s2]) : (unsigned short)0;
      }
    }
  }
  // kt[d][i] = K[i][d], bf16
  {
    unsigned short* ktd = kt_buf + (size_t)cid*(64*128);
    for (int idx = t; idx < 8192; idx += 256){
      int d = idx >> 6, i2 = idx & 63;
      ktd[idx] = f2bf(Ks[i2][d]);
    }
  }
}

// ---------- MFMA sequential scan; 64 blocks: bh = bid&15, cg = bid>>4 (32 cols each) ----------
__global__ __launch_bounds__(256) void seq_kernel(
    const unsigned short* __restrict__ wneg_buf, const float* __restrict__ u_buf,
    const unsigned short* __restrict__ kt_buf, const unsigned short* __restrict__ qk_buf,
    const unsigned short* __restrict__ qbh, float* __restrict__ o_buf){
  int bid = blockIdx.x;
  int bh = bid & 15, cg = bid >> 4;
  int b = bh >> 3, hh = bh & 7;
  int cbase = hh*DK_;
  int t = threadIdx.x;
  int wv = t >> 6, l = t & 63, g = l >> 4, lr = l & 15;

  __shared__ __align__(16) unsigned short Wl[8192];    // frag-ordered [fm(4)][kq(4)] chunks
  __shared__ __align__(16) unsigned short Ql[8192];
  __shared__ __align__(16) unsigned short Ktl[8192];   // [fn(8)][kq(2)] chunks
  __shared__ __align__(16) unsigned short qkl[4096];   // [fm(4)][kq(2)] chunks
  __shared__ __align__(16) float  Ul[2048];            // [64][32] linear
  __shared__ __align__(16) unsigned short Stl[32*136]; // S^T bf16, padded rows
  __shared__ __align__(16) float  Sf[32*132];          // S^T f32 master, padded
  __shared__ __align__(16) unsigned short vTl[32*72];  // v_new^T bf16, padded

  for (int z=t; z<32*132; z+=256) Sf[z] = 0.0f;
  for (int z=t; z<32*136; z+=256) Stl[z] = 0;
  __syncthreads();

  size_t cid0 = (size_t)bh*NC_;
  const unsigned short* wp  = wneg_buf + cid0*8192;
  const unsigned short* ktp = kt_buf  + cid0*8192;
  const unsigned short* qkp = qk_buf  + cid0*4096;
  const float*          up  = u_buf   + cid0*8192;
  const unsigned short* qp  = qbh + (size_t)(b*L_)*D_ + cbase;

  // per-thread staging source offsets (constant across ci)
  // W/Q rounds r: fm=r, kq=wv ; Kt rounds: fn=2r+(wv>>1), kq=wv&1 ; qk rounds r<2
  int wq_kq = wv;               // for W and Q
  int hv = wv >> 1, lv = wv & 1;

  for (int ci=0; ci<NC_; ++ci){
    // ---- stage chunk ci ----
    #pragma unroll
    for (int r=0;r<4;r++){
      gll16(wp + (size_t)(16*r + lr)*128 + wq_kq*32 + g*8, &Wl[(r*4+wv)*512 + l*8]);
      gll16(qp + (size_t)(16*r + lr)*D_  + wq_kq*32 + g*8, &Ql[(r*4+wv)*512 + l*8]);
      int fn = 2*r + hv;
      gll16(ktp + (size_t)(16*fn + lr)*64 + lv*32 + g*8, &Ktl[(r*4+wv)*512 + l*8]);
    }
    #pragma unroll
    for (int r=0;r<2;r++){
      int fm = 2*r + hv;
      gll16(qkp + (size_t)(16*fm + lr)*64 + lv*32 + g*8, &qkl[(r*4+wv)*512 + l*8]);
      int idx = r*256 + t;
      gll16(up + (size_t)(idx>>3)*128 + cg*32 + (idx&7)*4, &Ul[idx*4]);
    }
    __syncthreads();   // stage complete (vmcnt drained by compiler)

    // ---- phase B: v_new = U + (-W)@S ; wave wv owns row-tile mt=wv ----
    f32x4 accV[2];
    #pragma unroll
    for (int nt=0;nt<2;nt++){
      #pragma unroll
      for (int r=0;r<4;r++) accV[nt][r] = Ul[(16*wv + 4*g + r)*32 + 16*nt + lr];
    }
    #pragma unroll
    for (int kq=0;kq<4;kq++){
      short8 a = *(const short8*)&Wl[(wv*4+kq)*512 + l*8];
      short8 b0 = *(const short8*)&Stl[(0  + lr)*136 + kq*32 + g*8];
      short8 b1 = *(const short8*)&Stl[(16 + lr)*136 + kq*32 + g*8];
      accV[0] = __builtin_amdgcn_mfma_f32_16x16x32_bf16(a, b0, accV[0], 0,0,0);
      accV[1] = __builtin_amdgcn_mfma_f32_16x16x32_bf16(a, b1, accV[1], 0,0,0);
    }
    #pragma unroll
    for (int nt=0;nt<2;nt++){
      #pragma unroll
      for (int r=0;r<4;r++)
        vTl[(16*nt + lr)*72 + 16*wv + 4*g + r] = f2bf(accV[nt][r]);
    }
    __syncthreads();   // vT ready

    // ---- phase C: o = Q@S_prev + qk@v_new ----
    f32x4 accO[2];
    accO[0] = (f32x4){0.f,0.f,0.f,0.f}; accO[1] = (f32x4){0.f,0.f,0.f,0.f};
    #pragma unroll
    for (int kq=0;kq<4;kq++){
      short8 a = *(const short8*)&Ql[(wv*4+kq)*512 + l*8];
      short8 b0 = *(const short8*)&Stl[(0  + lr)*136 + kq*32 + g*8];
      short8 b1 = *(const short8*)&Stl[(16 + lr)*136 + kq*32 + g*8];
      accO[0] = __builtin_amdgcn_mfma_f32_16x16x32_bf16(a, b0, accO[0], 0,0,0);
      accO[1] = __builtin_amdgcn_mfma_f32_16x16x32_bf16(a, b1, accO[1], 0,0,0);
    }
    #pragma unroll
    for (int kq=0;kq<2;kq++){
      short8 a = *(const short8*)&qkl[(wv*2+kq)*512 + l*8];
      short8 b0 = *(const short8*)&vTl[(0  + lr)*72 + kq*32 + g*8];
      short8 b1 = *(const short8*)&vTl[(16 + lr)*72 + kq*32 + g*8];
      accO[0] = __builtin_amdgcn_mfma_f32_16x16x32_bf16(a, b0, accO[0], 0,0,0);
      accO[1] = __builtin_amdgcn_mfma_f32_16x16x32_bf16(a, b1, accO[1], 0,0,0);
    }
    {
      int n0 = b*L_ + ci*CS_;
      #pragma unroll
      for (int nt=0;nt<2;nt++){
        #pragma unroll
        for (int r=0;r<4;r++)
          o_buf[(size_t)(n0 + 16*wv + 4*g + r)*D_ + cbase + cg*32 + 16*nt + lr] = accO[nt][r];
      }
    }
    __syncthreads();   // St_prev reads done; safe to update

    // ---- phase D: S^T += v_new^T @ K ; wave wv owns d-tiles {2wv, 2wv+1} ----
    f32x4 accS[2][2];
    #pragma unroll
    for (int mc=0;mc<2;mc++)
      #pragma unroll
      for (int ntl=0;ntl<2;ntl++)
        #pragma unroll
        for (int r=0;r<4;r++)
          accS[mc][ntl][r] = Sf[(16*mc + 4*g + r)*132 + 32*wv + 16*ntl + lr];
    #pragma unroll
    for (int kq=0;kq<2;kq++){
      short8 a0 = *(const short8*)&vTl[(0  + lr)*72 + kq*32 + g*8];
      short8 a1 = *(const short8*)&vTl[(16 + lr)*72 + kq*32 + g*8];
      short8 b0 = *(const short8*)&Ktl[((2*wv+0)*2 + kq)*512 + l*8];
      short8 b1 = *(const short8*)&Ktl[((2*wv+1)*2 + kq)*512 + l*8];
      accS[0][0] = __builtin_amdgcn_mfma_f32_16x16x32_bf16(a0, b0, accS[0][0], 0,0,0);
      accS[0][1] = __builtin_amdgcn_mfma_f32_16x16x32_bf16(a0, b1, accS[0][1], 0,0,0);
      accS[1][0] = __builtin_amdgcn_mfma_f32_16x16x32_bf16(a1, b0, accS[1][0], 0,0,0);
      accS[1][1] = __builtin_amdgcn_mfma_f32_16x16x32_bf16(a1, b1, accS[1][1], 0,0,0);
    }
    #pragma unroll
    for (int mc=0;mc<2;mc++){
      #pragma unroll
      for (int ntl=0;ntl<2;ntl++){
        #pragma unroll
        for (int r=0;r<4;r++){
          int c = 16*mc + 4*g + r, d = 32*wv + 16*ntl + lr;
          float val = accS[mc][ntl][r];
          Sf[c*132 + d] = val;
          Stl[c*136 + d] = f2bf(val);
        }
      }
    }
    __syncthreads();   // S updated before next stage overwrites inputs

    wp += 8192; ktp += 8192; qkp += 4096; up += 8192; qp += (size_t)CS_*D_;
  }
}

// ---------- per-head RMSNorm over DV=128, bf16 out ----------
__global__ __launch_bounds__(256) void head_rmsnorm_kernel(const float* __restrict__ o,
    const float* __restrict__ w, unsigned short* __restrict__ out){
  int n = blockIdx.x, t = threadIdx.x;
  float4 v = ((const float4*)(o + (size_t)n*D_))[t];
  float ss = v.x*v.x+v.y*v.y+v.z*v.z+v.w*v.w;
  #pragma unroll
  for (int m=16;m>0;m>>=1) ss += __shfl_xor(ss, m, 64);
  float rs = rsqrtf(ss*(1.0f/DK_) + 1e-6f);
  float4 wv = ((const float4*)w)[t & 31];
  float4 u; u.x=v.x*rs*wv.x; u.y=v.y*rs*wv.y; u.z=v.z*rs*wv.z; u.w=v.w*rs*wv.w;
  ushort4 r4; r4.x=f2bf(u.x); r4.y=f2bf(u.y); r4.z=f2bf(u.z); r4.w=f2bf(u.w);
  ((ushort4*)(out + (size_t)n*D_))[t] = r4;
}

extern "C" void kernel_launch(void* const* d_in, const int* in_sizes, int n_in,
                              void* d_out, int out_size, void* d_ws, size_t ws_size,
                              hipStream_t stream){
  const float* x      = (const float*)d_in[0];
  const float* norm_w = (const float*)d_in[1];
  const float* Wq     = (const float*)d_in[2];
  const float* Wk     = (const float*)d_in[3];
  const float* Wv     = (const float*)d_in[4];
  const float* Wb     = (const float*)d_in[5];
  const float* conv_q = (const float*)d_in[6];
  const float* conv_k = (const float*)d_in[7];
  const float* conv_v = (const float*)d_in[8];
  const float* onw    = (const float*)d_in[9];
  const float* Wo     = (const float*)d_in[10];
  float* out = (float*)d_out;

  const size_t NB = (size_t)NR_*D_;           // 8,388,608 floats
  float* ws   = (float*)d_ws;
  float* h    = ws;            // f32 h; later obb (bf16)
  float* b1   = ws + NB;       // qlin -> wneg(bf16) + kt(bf16)
  float* b2   = ws + 2*NB;     // klin -> u (f32)
  float* b3   = ws + 3*NB;     // vlin -> qk(bf16) + qbh(bf16)
  float* qb   = ws + 4*NB;     // hb (bf16) aliases here until conv_q runs
  float* kb   = ws + 5*NB;
  float* vb   = ws + 6*NB;     // v f32 -> o f32 (seq output)
  float* qkb_old = ws + 7*NB;  // (region kept for betab/wt offsets)
  float* betab= qkb_old + (size_t)1024*4096;
  unsigned short* wtq = (unsigned short*)(betab + 65536);
  unsigned short* wtk = wtq + (size_t)D_*D_;
  unsigned short* wtv = wtk + (size_t)D_*D_;
  unsigned short* wto = wtv + (size_t)D_*D_;
  unsigned short* hb  = (unsigned short*)qb;
  unsigned short* obb = (unsigned short*)h;
  unsigned short* wneg= (unsigned short*)b1;
  unsigned short* ktb = wneg + NB;            // second half of b1
  unsigned short* qkbf= (unsigned short*)b3;  // 4,194,304 ushorts
  unsigned short* qbh = qkbf + (size_t)1024*4096;

  rmsnorm_kernel<<<NR_, 256, 0, stream>>>(x, norm_w, h, hb);
  dim3 tg(16,16);
  transpose_bf16_kernel<<<tg, 256, 0, stream>>>(Wq, wtq);
  transpose_bf16_kernel<<<tg, 256, 0, stream>>>(Wk, wtk);
  transpose_bf16_kernel<<<tg, 256, 0, stream>>>(Wv, wtv);
  transpose_bf16_kernel<<<tg, 256, 0, stream>>>(Wo, wto);
  dim3 gg(D_/128, NR_/128);
  gemm_bf16<<<gg, 256, 0, stream>>>(hb, wtq, nullptr, b1, D_, D_);
  gemm_bf16<<<gg, 256, 0, stream>>>(hb, wtk, nullptr, b2, D_, D_);
  gemm_bf16<<<gg, 256, 0, stream>>>(hb, wtv, nullptr, b3, D_, D_);
  beta_kernel<<<NR_, 256, 0, stream>>>(h, Wb, betab);
  conv_silu_kernel<<<(int)(NB/256), 256, 0, stream>>>(b1, conv_q, qb);
  conv_silu_kernel<<<(int)(NB/256), 256, 0, stream>>>(b2, conv_k, kb);
  conv_silu_kernel<<<(int)(NB/256), 256, 0, stream>>>(b3, conv_v, vb);
  const float qscale = 0.08838834764831845f;  // DK^-0.5
  silu_l2norm_kernel<<<NR_, 256, 0, stream>>>(qb, qscale, qbh);
  silu_l2norm_kernel<<<NR_, 256, 0, stream>>>(kb, 1.0f, nullptr);
  chunk_local_kernel<<<dim3(NC_, 16), 256, 0, stream>>>(qb, kb, vb, betab,
      wneg, b2, qkbf, ktb);
  seq_kernel<<<64, 256, 0, stream>>>(wneg, b2, ktb, qkbf, qbh, vb);
  head_rmsnorm_kernel<<<NR_, 256, 0, stream>>>(vb, onw, obb);
  gemm_bf16<<<gg, 256, 0, stream>>>(obb, wto, x, out, D_, D_);
  (void)in_sizes; (void)n_in; (void)out_size; (void)ws_size;
}

// Round 6
// 744.197 us; speedup vs baseline: 2.6580x; 1.0445x over previous
//
#include <hip/hip_runtime.h>
#include <hip/hip_bf16.h>

// DeltaNet block. B=2 L=4096 D=1024 H=8 DK=DV=128 KCONV=4 CHUNK=64
// Round 6: seq_kernel double-buffer prefetch + raw barriers + counted vmcnt,
// S-state in registers; QKV projections fused into one N=3072 MFMA GEMM.
#define B_ 2
#define L_ 4096
#define D_ 1024
#define H_ 8
#define DK_ 128
#define NR_ (B_*L_)      // 8192 rows
#define NC_ 64           // chunks per sequence
#define CS_ 64           // chunk size

typedef __attribute__((ext_vector_type(8))) short short8;
typedef __attribute__((ext_vector_type(4))) float f32x4;

__device__ __forceinline__ float sigmf(float x){ return 1.0f/(1.0f+__expf(-x)); }
__device__ __forceinline__ float siluf(float x){ return x/(1.0f+__expf(-x)); }
__device__ __forceinline__ unsigned short f2bf(float f){
  __hip_bfloat16 h = __float2bfloat16(f);
  return *reinterpret_cast<unsigned short*>(&h);
}
__device__ __forceinline__ void gll16(const void* g, void* l){
  __builtin_amdgcn_global_load_lds((const __attribute__((address_space(1))) void*)g,
      (__attribute__((address_space(3))) void*)l, 16, 0, 0);
}

// ---------- RMSNorm over D, dual f32 + bf16 output ----------
__global__ __launch_bounds__(256) void rmsnorm_kernel(const float* __restrict__ x,
    const float* __restrict__ w, float* __restrict__ h, unsigned short* __restrict__ hb){
  int n = blockIdx.x; int t = threadIdx.x;
  float4 v = ((const float4*)(x + (size_t)n*D_))[t];
  float ss = v.x*v.x + v.y*v.y + v.z*v.z + v.w*v.w;
  #pragma unroll
  for (int m=32;m>0;m>>=1) ss += __shfl_xor(ss, m, 64);
  __shared__ float red[4];
  if ((t&63)==0) red[t>>6] = ss;
  __syncthreads();
  ss = red[0]+red[1]+red[2]+red[3];
  float rs = rsqrtf(ss*(1.0f/D_) + 1e-6f);
  float4 wv = ((const float4*)w)[t];
  float4 o; o.x=v.x*rs*wv.x; o.y=v.y*rs*wv.y; o.z=v.z*rs*wv.z; o.w=v.w*rs*wv.w;
  ((float4*)(h + (size_t)n*D_))[t] = o;
  ushort4 ob4; ob4.x=f2bf(o.x); ob4.y=f2bf(o.y); ob4.z=f2bf(o.z); ob4.w=f2bf(o.w);
  ((ushort4*)(hb + (size_t)n*D_))[t] = ob4;
}

// ---------- transpose + f32->bf16: W[1024][1024] -> Wt[n][k] ----------
__global__ __launch_bounds__(256) void transpose_bf16_kernel(const float* __restrict__ W,
    unsigned short* __restrict__ Wt){
  __shared__ float tile[64][65];
  int bi = blockIdx.y, bj = blockIdx.x;
  int tx = threadIdx.x & 63, tg = threadIdx.x >> 6;
  #pragma unroll
  for (int i=0;i<16;i++){
    int r = tg*16 + i;
    tile[r][tx] = W[(size_t)(bi*64 + r)*D_ + bj*64 + tx];
  }
  __syncthreads();
  #pragma unroll
  for (int i=0;i<16;i++){
    int r = tg*16 + i;
    Wt[(size_t)(bj*64 + r)*D_ + bi*64 + tx] = f2bf(tile[tx][r]);
  }
}

// ---------- bf16 MFMA GEMM: C[M,N] f32 = A[M,K]bf16 @ Bt[N,K]bf16^T (+R) ----------
__global__ __launch_bounds__(256) void gemm_bf16(const unsigned short* __restrict__ A,
    const unsigned short* __restrict__ Bt, const float* __restrict__ R,
    float* __restrict__ C, int N, int K){
  __shared__ __align__(16) unsigned short Al[4096];
  __shared__ __align__(16) unsigned short Bl[4096];
  int t = threadIdx.x, w = t>>6, l = t&63;
  int wm = w&1, wn = w>>1;
  int row0 = blockIdx.y*128, col0 = blockIdx.x*128;
  int lr = l&15, lk = l>>4;
  const unsigned short* ga0 = A  + (size_t)(row0 + w*16     + lr)*K + lk*8;
  const unsigned short* ga1 = A  + (size_t)(row0 + (w+4)*16 + lr)*K + lk*8;
  const unsigned short* gb0 = Bt + (size_t)(col0 + w*16     + lr)*K + lk*8;
  const unsigned short* gb1 = Bt + (size_t)(col0 + (w+4)*16 + lr)*K + lk*8;
  unsigned short* la0 = &Al[(w*64 + l)*8];
  unsigned short* la1 = &Al[((w+4)*64 + l)*8];
  unsigned short* lb0 = &Bl[(w*64 + l)*8];
  unsigned short* lb1 = &Bl[((w+4)*64 + l)*8];
  f32x4 acc[4][4];
  #pragma unroll
  for (int i=0;i<4;i++)
    #pragma unroll
    for (int j=0;j<4;j++) acc[i][j] = (f32x4){0.f,0.f,0.f,0.f};
  for (int k0=0;k0<K;k0+=32){
    gll16(ga0 + k0, la0);
    gll16(ga1 + k0, la1);
    gll16(gb0 + k0, lb0);
    gll16(gb1 + k0, lb1);
    __syncthreads();
    short8 af[4], bfr[4];
    #pragma unroll
    for (int i=0;i<4;i++) af[i]  = *(const short8*)&Al[((wm*4+i)*64 + l)*8];
    #pragma unroll
    for (int j=0;j<4;j++) bfr[j] = *(const short8*)&Bl[((wn*4+j)*64 + l)*8];
    #pragma unroll
    for (int i=0;i<4;i++)
      #pragma unroll
      for (int j=0;j<4;j++)
        acc[i][j] = __builtin_amdgcn_mfma_f32_16x16x32_bf16(af[i], bfr[j], acc[i][j], 0,0,0);
    __syncthreads();
  }
  int orow = row0 + wm*64 + (l>>4)*4;
  int ocol = col0 + wn*64 + (l&15);
  #pragma unroll
  for (int i=0;i<4;i++){
    #pragma unroll
    for (int j=0;j<4;j++){
      #pragma unroll
      for (int r=0;r<4;r++){
        size_t idx = (size_t)(orow + i*16 + r)*N + ocol + j*16;
        float res = R ? R[idx] : 0.0f;
        C[idx] = acc[i][j][r] + res;
      }
    }
  }
}

// ---------- beta = sigmoid(h @ Wb[1024,8]) ----------
__global__ __launch_bounds__(256) void beta_kernel(const float* __restrict__ h,
    const float* __restrict__ Wb, float* __restrict__ beta){
  int n = blockIdx.x, t = threadIdx.x;
  const float* hr = h + (size_t)n*D_;
  float p[8] = {};
  for (int kx=t; kx<D_; kx+=256){
    float hv = hr[kx];
    const float* wr = Wb + (size_t)kx*H_;
    #pragma unroll
    for (int j=0;j<8;j++) p[j] += hv*wr[j];
  }
  #pragma unroll
  for (int m=32;m>0;m>>=1){
    #pragma unroll
    for (int j=0;j<8;j++) p[j] += __shfl_xor(p[j], m, 64);
  }
  __shared__ float red[4][8];
  if ((t&63)==0){
    #pragma unroll
    for (int j=0;j<8;j++) red[t>>6][j] = p[j];
  }
  __syncthreads();
  if (t < 8){
    float s = red[0][t]+red[1][t]+red[2][t]+red[3][t];
    beta[(size_t)n*H_ + t] = sigmf(s);
  }
}

// ---------- causal depthwise conv(K=4) + silu; strided input (fused qkv) ----------
__global__ __launch_bounds__(256) void conv_silu_kernel(const float* __restrict__ in,
    const float* __restrict__ w, float* __restrict__ out, int ld){
  size_t idx = (size_t)blockIdx.x*256 + threadIdx.x;
  int c = (int)(idx & (D_-1));
  int n = (int)(idx >> 10);
  int l = n & (L_-1);
  const float* src = in + (size_t)n*ld + c;
  float4 wv = ((const float4*)w)[c];
  float acc = wv.w * src[0];
  if (l >= 1) acc += wv.z * src[-ld];
  if (l >= 2) acc += wv.y * src[-2*ld];
  if (l >= 3) acc += wv.x * src[-3*ld];
  out[(size_t)n*D_ + c] = siluf(acc);
}

// ---------- second silu + per-head l2norm (+optional q scale, optional bf16 copy) ----------
__global__ __launch_bounds__(256) void silu_l2norm_kernel(float* __restrict__ a, float scale,
    unsigned short* __restrict__ ob){
  int n = blockIdx.x, t = threadIdx.x;
  float* row = a + (size_t)n*D_;
  float4 v = ((const float4*)row)[t];
  float4 u; u.x=siluf(v.x); u.y=siluf(v.y); u.z=siluf(v.z); u.w=siluf(v.w);
  float ss = u.x*u.x+u.y*u.y+u.z*u.z+u.w*u.w;
  #pragma unroll
  for (int m=16;m>0;m>>=1) ss += __shfl_xor(ss, m, 64);
  float rs = rsqrtf(ss + 1e-6f) * scale;
  u.x*=rs; u.y*=rs; u.z*=rs; u.w*=rs;
  ((float4*)row)[t] = u;
  if (ob){
    ushort4 r4; r4.x=f2bf(u.x); r4.y=f2bf(u.y); r4.z=f2bf(u.z); r4.w=f2bf(u.w);
    ((ushort4*)(ob + (size_t)n*D_))[t] = r4;
  }
}

// ---------- chunk-local: w=-A^-1(bk) [bf16], u=A^-1(bv) [f32], qk masked [bf16], kt=K^T [bf16] ----------
__global__ __launch_bounds__(256) void chunk_local_kernel(
    const float* __restrict__ q, const float* __restrict__ k, const float* __restrict__ v,
    const float* __restrict__ beta, unsigned short* __restrict__ wneg_buf,
    float* __restrict__ u_buf, unsigned short* __restrict__ qk_buf,
    unsigned short* __restrict__ kt_buf){
  int ci = blockIdx.x, bh = blockIdx.y;
  int b = bh >> 3, hh = bh & 7;
  int n0 = b*L_ + ci*CS_;
  int cbase = hh*DK_;
  int cid = bh*NC_ + ci;
  __shared__ float Ks[64][132];
  __shared__ float Als[64*68];
  __shared__ float rowW[144];
  __shared__ float rowU[144];
  __shared__ float bs[64];
  int t = threadIdx.x;
  {
    int r = t >> 2, c0 = (t & 3)*32;
    const float* kr = k + (size_t)(n0+r)*D_ + cbase + c0;
    #pragma unroll
    for (int m=0;m<32;m+=4) *(float4*)&Ks[r][c0+m] = *(const float4*)&kr[m];
  }
  if (t < 64) bs[t] = beta[(size_t)(n0+t)*H_ + hh];
  __syncthreads();
  int ti = t >> 4, tj = t & 15;
  {
    float cc[4][4] = {};
    #pragma unroll 2
    for (int d=0; d<128; d+=4){
      float4 ar[4], br[4];
      #pragma unroll
      for (int r2=0;r2<4;r2++) ar[r2] = *(const float4*)&Ks[ti+16*r2][d];
      #pragma unroll
      for (int s2=0;s2<4;s2++) br[s2] = *(const float4*)&Ks[tj+16*s2][d];
      #pragma unroll
      for (int r2=0;r2<4;r2++){
        #pragma unroll
        for (int s2=0;s2<4;s2++){
          cc[r2][s2] += ar[r2].x*br[s2].x + ar[r2].y*br[s2].y
                      + ar[r2].z*br[s2].z + ar[r2].w*br[s2].w;
        }
      }
    }
    #pragma unroll
    for (int r2=0;r2<4;r2++){
      #pragma unroll
      for (int s2=0;s2<4;s2++){
        int i2 = ti + 16*r2, j2 = tj + 16*s2;
        Als[i2*68 + j2] = (j2 < i2) ? bs[i2]*cc[r2][s2] : 0.0f;
      }
    }
  }
  __syncthreads();
  int i = t >> 2, part = t & 3, ds = part*32, dp = part*36;
  float wreg[32], ureg[32];
  {
    float bi = bs[i];
    const float* vr = v + (size_t)(n0+i)*D_ + cbase + ds;
    #pragma unroll
    for (int m=0;m<32;m++) wreg[m] = bi * Ks[i][ds+m];
    #pragma unroll
    for (int m=0;m<32;m+=4){
      float4 vv = *(const float4*)&vr[m];
      ureg[m+0]=bi*vv.x; ureg[m+1]=bi*vv.y; ureg[m+2]=bi*vv.z; ureg[m+3]=bi*vv.w;
    }
  }
  for (int j=0;j<63;j++){
    if (i == j){
      #pragma unroll
      for (int m=0;m<32;m++){ rowW[dp+m]=wreg[m]; rowU[dp+m]=ureg[m]; }
    }
    __syncthreads();
    if (i > j){
      float aj = Als[i*68 + j];
      #pragma unroll
      for (int m=0;m<32;m++){ wreg[m] -= aj*rowW[dp+m]; ureg[m] -= aj*rowU[dp+m]; }
    }
    __syncthreads();
  }
  {
    unsigned short* wd = wneg_buf + (size_t)cid*(64*128) + (size_t)i*128 + ds;
    float* ud = u_buf + (size_t)cid*(64*128) + (size_t)i*128 + ds;
    #pragma unroll
    for (int m=0;m<32;m+=4){
      ushort4 f; f.x=f2bf(-wreg[m]); f.y=f2bf(-wreg[m+1]); f.z=f2bf(-wreg[m+2]); f.w=f2bf(-wreg[m+3]);
      *(ushort4*)&wd[m] = f;
      float4 g; g.x=ureg[m]; g.y=ureg[m+1]; g.z=ureg[m+2]; g.w=ureg[m+3];
      *(float4*)&ud[m] = g;
    }
  }
  __syncthreads();
  {
    const float* qbase = q + (size_t)n0*D_ + cbase;
    float cc[4][4] = {};
    #pragma unroll 2
    for (int d=0; d<128; d+=4){
      float4 ar[4], br[4];
      #pragma unroll
      for (int r2=0;r2<4;r2++) ar[r2] = *(const float4*)&qbase[(size_t)(ti+16*r2)*D_ + d];
      #pragma unroll
      for (int s2=0;s2<4;s2++) br[s2] = *(const float4*)&Ks[tj+16*s2][d];
      #pragma unroll
      for (int r2=0;r2<4;r2++){
        #pragma unroll
        for (int s2=0;s2<4;s2++){
          cc[r2][s2] += ar[r2].x*br[s2].x + ar[r2].y*br[s2].y
                      + ar[r2].z*br[s2].z + ar[r2].w*br[s2].w;
        }
      }
    }
    unsigned short* qkd = qk_buf + (size_t)cid*4096;
    #pragma unroll
    for (int r2=0;r2<4;r2++){
      #pragma unroll
      for (int s2=0;s2<4;s2++){
        int i2 = ti+16*r2, j2 = tj+16*s2;
        qkd[i2*64 + j2] = (j2 <= i2) ? f2bf(cc[r2][s2]) : (unsigned short)0;
      }
    }
  }
  {
    unsigned short* ktd = kt_buf + (size_t)cid*(64*128);
    for (int idx = t; idx < 8192; idx += 256){
      int d = idx >> 6, i2 = idx & 63;
      ktd[idx] = f2bf(Ks[i2][d]);
    }
  }
}

// ---------- MFMA sequential scan, double-buffered prefetch, raw barriers ----------
__global__ __launch_bounds__(256) void seq_kernel(
    const unsigned short* __restrict__ wneg_buf, const float* __restrict__ u_buf,
    const unsigned short* __restrict__ kt_buf, const unsigned short* __restrict__ qk_buf,
    const unsigned short* __restrict__ qbh, float* __restrict__ o_buf){
  int bid = blockIdx.x;
  int bh = bid & 15, cg = bid >> 4;
  int b = bh >> 3, hh = bh & 7;
  int cbase = hh*DK_;
  int t = threadIdx.x;
  int wv = t >> 6, l = t & 63, g = l >> 4, lr = l & 15;

  __shared__ __align__(16) unsigned short Wl[2][8192];
  __shared__ __align__(16) unsigned short Ql[2][8192];
  __shared__ __align__(16) unsigned short Ktl[2][8192];
  __shared__ __align__(16) unsigned short qkl[2][4096];
  __shared__ __align__(16) float  Ul[2][2048];
  __shared__ __align__(16) unsigned short Stl[32*136]; // S^T bf16, padded rows
  __shared__ __align__(16) unsigned short vTl[32*72];  // v_new^T bf16, padded

  // S^T f32 master lives in registers: thread owns (c = 16mc+4g+r, d = 32wv+16ntl+lr)
  f32x4 Sacc[2][2];
  #pragma unroll
  for (int mc=0;mc<2;mc++)
    #pragma unroll
    for (int ntl=0;ntl<2;ntl++) Sacc[mc][ntl] = (f32x4){0.f,0.f,0.f,0.f};

  for (int z=t; z<32*136; z+=256) Stl[z] = 0;
  __syncthreads();

  size_t cid0 = (size_t)bh*NC_;
  const unsigned short* wb_  = wneg_buf + cid0*8192;
  const unsigned short* ktb_ = kt_buf  + cid0*8192;
  const unsigned short* qkb_ = qk_buf  + cid0*4096;
  const float*          ub_  = u_buf   + cid0*8192;
  const unsigned short* qb_  = qbh + (size_t)(b*L_)*D_ + cbase;

  int hv = wv >> 1, lv = wv & 1;

  #define STAGE(BI, CI) do { \
    const unsigned short* wp  = wb_  + (size_t)(CI)*8192; \
    const unsigned short* kp  = ktb_ + (size_t)(CI)*8192; \
    const unsigned short* qkp = qkb_ + (size_t)(CI)*4096; \
    const float*          up  = ub_  + (size_t)(CI)*8192; \
    const unsigned short* qp  = qb_  + (size_t)(CI)*CS_*D_; \
    _Pragma("unroll") \
    for (int r=0;r<4;r++){ \
      gll16(wp + (size_t)(16*r + lr)*128 + wv*32 + g*8, &Wl[BI][(r*4+wv)*512 + l*8]); \
      gll16(qp + (size_t)(16*r + lr)*D_  + wv*32 + g*8, &Ql[BI][(r*4+wv)*512 + l*8]); \
      int fn = 2*r + hv; \
      gll16(kp + (size_t)(16*fn + lr)*64 + lv*32 + g*8, &Ktl[BI][(r*4+wv)*512 + l*8]); \
    } \
    _Pragma("unroll") \
    for (int r=0;r<2;r++){ \
      int fm = 2*r + hv; \
      gll16(qkp + (size_t)(16*fm + lr)*64 + lv*32 + g*8, &qkl[BI][(r*4+wv)*512 + l*8]); \
      int idx = r*256 + t; \
      gll16(up + (size_t)(idx>>3)*128 + cg*32 + (idx&7)*4, &Ul[BI][idx*4]); \
    } \
  } while(0)

  // prime buffer 0 with chunk 0
  STAGE(0, 0);
  asm volatile("s_waitcnt vmcnt(0)" ::: "memory");
  __builtin_amdgcn_s_barrier();
  __builtin_amdgcn_sched_barrier(0);

  int cur = 0;
  for (int ci=0; ci<NC_; ++ci){
    int cn = (ci+1 < NC_) ? ci+1 : ci;
    STAGE(cur^1, cn);   // prefetch next chunk; stays in flight across phase barriers

    // ---- phase B: v_new = U + (-W)@S ----
    f32x4 accV[2];
    #pragma unroll
    for (int nt=0;nt<2;nt++){
      #pragma unroll
      for (int r=0;r<4;r++) accV[nt][r] = Ul[cur][(16*wv + 4*g + r)*32 + 16*nt + lr];
    }
    #pragma unroll
    for (int kq=0;kq<4;kq++){
      short8 a  = *(const short8*)&Wl[cur][(wv*4+kq)*512 + l*8];
      short8 b0 = *(const short8*)&Stl[(0  + lr)*136 + kq*32 + g*8];
      short8 b1 = *(const short8*)&Stl[(16 + lr)*136 + kq*32 + g*8];
      accV[0] = __builtin_amdgcn_mfma_f32_16x16x32_bf16(a, b0, accV[0], 0,0,0);
      accV[1] = __builtin_amdgcn_mfma_f32_16x16x32_bf16(a, b1, accV[1], 0,0,0);
    }
    #pragma unroll
    for (int nt=0;nt<2;nt++){
      #pragma unroll
      for (int r=0;r<4;r++)
        vTl[(16*nt + lr)*72 + 16*wv + 4*g + r] = f2bf(accV[nt][r]);
    }
    asm volatile("s_waitcnt lgkmcnt(0)" ::: "memory");
    __builtin_amdgcn_s_barrier();
    __builtin_amdgcn_sched_barrier(0);

    // ---- phase C: o = Q@S_prev + qk@v_new ----
    f32x4 accO[2];
    accO[0] = (f32x4){0.f,0.f,0.f,0.f}; accO[1] = (f32x4){0.f,0.f,0.f,0.f};
    #pragma unroll
    for (int kq=0;kq<4;kq++){
      short8 a  = *(const short8*)&Ql[cur][(wv*4+kq)*512 + l*8];
      short8 b0 = *(const short8*)&Stl[(0  + lr)*136 + kq*32 + g*8];
      short8 b1 = *(const short8*)&Stl[(16 + lr)*136 + kq*32 + g*8];
      accO[0] = __builtin_amdgcn_mfma_f32_16x16x32_bf16(a, b0, accO[0], 0,0,0);
      accO[1] = __builtin_amdgcn_mfma_f32_16x16x32_bf16(a, b1, accO[1], 0,0,0);
    }
    #pragma unroll
    for (int kq=0;kq<2;kq++){
      short8 a  = *(const short8*)&qkl[cur][(wv*2+kq)*512 + l*8];
      short8 b0 = *(const short8*)&vTl[(0  + lr)*72 + kq*32 + g*8];
      short8 b1 = *(const short8*)&vTl[(16 + lr)*72 + kq*32 + g*8];
      accO[0] = __builtin_amdgcn_mfma_f32_16x16x32_bf16(a, b0, accO[0], 0,0,0);
      accO[1] = __builtin_amdgcn_mfma_f32_16x16x32_bf16(a, b1, accO[1], 0,0,0);
    }
    {
      int n0 = b*L_ + ci*CS_;
      #pragma unroll
      for (int nt=0;nt<2;nt++){
        #pragma unroll
        for (int r=0;r<4;r++)
          o_buf[(size_t)(n0 + 16*wv + 4*g + r)*D_ + cbase + cg*32 + 16*nt + lr] = accO[nt][r];
      }
    }
    asm volatile("s_waitcnt lgkmcnt(0)" ::: "memory");
    __builtin_amdgcn_s_barrier();
    __builtin_amdgcn_sched_barrier(0);

    // ---- phase D: S^T += v_new^T @ K (registers) ----
    #pragma unroll
    for (int kq=0;kq<2;kq++){
      short8 a0 = *(const short8*)&vTl[(0  + lr)*72 + kq*32 + g*8];
      short8 a1 = *(const short8*)&vTl[(16 + lr)*72 + kq*32 + g*8];
      short8 b0 = *(const short8*)&Ktl[cur][((2*wv+0)*2 + kq)*512 + l*8];
      short8 b1 = *(const short8*)&Ktl[cur][((2*wv+1)*2 + kq)*512 + l*8];
      Sacc[0][0] = __builtin_amdgcn_mfma_f32_16x16x32_bf16(a0, b0, Sacc[0][0], 0,0,0);
      Sacc[0][1] = __builtin_amdgcn_mfma_f32_16x16x32_bf16(a0, b1, Sacc[0][1], 0,0,0);
      Sacc[1][0] = __builtin_amdgcn_mfma_f32_16x16x32_bf16(a1, b0, Sacc[1][0], 0,0,0);
      Sacc[1][1] = __builtin_amdgcn_mfma_f32_16x16x32_bf16(a1, b1, Sacc[1][1], 0,0,0);
    }
    #pragma unroll
    for (int mc=0;mc<2;mc++){
      #pragma unroll
      for (int ntl=0;ntl<2;ntl++){
        #pragma unroll
        for (int r=0;r<4;r++)
          Stl[(16*mc + 4*g + r)*136 + 32*wv + 16*ntl + lr] = f2bf(Sacc[mc][ntl][r]);
      }
    }
    asm volatile("s_waitcnt lgkmcnt(0)" ::: "memory");
    asm volatile("s_waitcnt vmcnt(4)" ::: "memory");  // prefetch (oldest 16) retired; o-stores may fly
    __builtin_amdgcn_s_barrier();
    __builtin_amdgcn_sched_barrier(0);
    cur ^= 1;
  }
  #undef STAGE
}

// ---------- per-head RMSNorm over DV=128, bf16 out ----------
__global__ __launch_bounds__(256) void head_rmsnorm_kernel(const float* __restrict__ o,
    const float* __restrict__ w, unsigned short* __restrict__ out){
  int n = blockIdx.x, t = threadIdx.x;
  float4 v = ((const float4*)(o + (size_t)n*D_))[t];
  float ss = v.x*v.x+v.y*v.y+v.z*v.z+v.w*v.w;
  #pragma unroll
  for (int m=16;m>0;m>>=1) ss += __shfl_xor(ss, m, 64);
  float rs = rsqrtf(ss*(1.0f/DK_) + 1e-6f);
  float4 wv = ((const float4*)w)[t & 31];
  float4 u; u.x=v.x*rs*wv.x; u.y=v.y*rs*wv.y; u.z=v.z*rs*wv.z; u.w=v.w*rs*wv.w;
  ushort4 r4; r4.x=f2bf(u.x); r4.y=f2bf(u.y); r4.z=f2bf(u.z); r4.w=f2bf(u.w);
  ((ushort4*)(out + (size_t)n*D_))[t] = r4;
}

extern "C" void kernel_launch(void* const* d_in, const int* in_sizes, int n_in,
                              void* d_out, int out_size, void* d_ws, size_t ws_size,
                              hipStream_t stream){
  const float* x      = (const float*)d_in[0];
  const float* norm_w = (const float*)d_in[1];
  const float* Wq     = (const float*)d_in[2];
  const float* Wk     = (const float*)d_in[3];
  const float* Wv     = (const float*)d_in[4];
  const float* Wb     = (const float*)d_in[5];
  const float* conv_q = (const float*)d_in[6];
  const float* conv_k = (const float*)d_in[7];
  const float* conv_v = (const float*)d_in[8];
  const float* onw    = (const float*)d_in[9];
  const float* Wo     = (const float*)d_in[10];
  float* out = (float*)d_out;

  const size_t NB = (size_t)NR_*D_;           // 8,388,608 floats
  float* ws   = (float*)d_ws;
  float* h    = ws;                 // f32 h; later obb (bf16)
  float* qkv  = ws + NB;            // fused [8192][3072] f32; later recurrence buffers
  float* qb   = ws + 4*NB;          // hb (bf16) aliases here until conv_q runs
  float* kb   = ws + 5*NB;
  float* vb   = ws + 6*NB;          // v f32 -> o f32 (seq output)
  float* betab= ws + 7*NB;          // 65536 floats
  unsigned short* wtq = (unsigned short*)(betab + 65536);  // q,k,v contiguous + o
  unsigned short* wtk = wtq + (size_t)D_*D_;
  unsigned short* wtv = wtk + (size_t)D_*D_;
  unsigned short* wto = wtv + (size_t)D_*D_;
  unsigned short* hb  = (unsigned short*)qb;
  unsigned short* obb = (unsigned short*)h;
  // recurrence buffers inside dead qkv region (88MB <= 100.66MB):
  unsigned short* wneg = (unsigned short*)qkv;             // 16MB
  unsigned short* ktb  = wneg + (size_t)8*1024*1024;       // 16MB
  unsigned short* qkbf = ktb  + (size_t)8*1024*1024;       // 8MB
  unsigned short* qbh  = qkbf + (size_t)4*1024*1024;       // 16MB
  float*          ubuf = (float*)(qbh + (size_t)8*1024*1024); // 32MB

  rmsnorm_kernel<<<NR_, 256, 0, stream>>>(x, norm_w, h, hb);
  dim3 tg(16,16);
  transpose_bf16_kernel<<<tg, 256, 0, stream>>>(Wq, wtq);
  transpose_bf16_kernel<<<tg, 256, 0, stream>>>(Wk, wtk);
  transpose_bf16_kernel<<<tg, 256, 0, stream>>>(Wv, wtv);
  transpose_bf16_kernel<<<tg, 256, 0, stream>>>(Wo, wto);
  // fused QKV projection: N = 3072
  dim3 gq(3*D_/128, NR_/128);   // (24, 64)
  gemm_bf16<<<gq, 256, 0, stream>>>(hb, wtq, nullptr, qkv, 3*D_, D_);
  beta_kernel<<<NR_, 256, 0, stream>>>(h, Wb, betab);
  conv_silu_kernel<<<(int)(NB/256), 256, 0, stream>>>(qkv,        conv_q, qb, 3*D_);
  conv_silu_kernel<<<(int)(NB/256), 256, 0, stream>>>(qkv + D_,   conv_k, kb, 3*D_);
  conv_silu_kernel<<<(int)(NB/256), 256, 0, stream>>>(qkv + 2*D_, conv_v, vb, 3*D_);
  const float qscale = 0.08838834764831845f;  // DK^-0.5
  silu_l2norm_kernel<<<NR_, 256, 0, stream>>>(qb, qscale, qbh);
  silu_l2norm_kernel<<<NR_, 256, 0, stream>>>(kb, 1.0f, nullptr);
  chunk_local_kernel<<<dim3(NC_, 16), 256, 0, stream>>>(qb, kb, vb, betab,
      wneg, ubuf, qkbf, ktb);
  seq_kernel<<<64, 256, 0, stream>>>(wneg, ubuf, ktb, qkbf, qbh, vb);
  head_rmsnorm_kernel<<<NR_, 256, 0, stream>>>(vb, onw, obb);
  dim3 gg(D_/128, NR_/128);
  gemm_bf16<<<gg, 256, 0, stream>>>(obb, wto, x, out, D_, D_);
  (void)in_sizes; (void)n_in; (void)out_size; (void)ws_size;
}

// Round 8
// 688.622 us; speedup vs baseline: 2.8725x; 1.0807x over previous
//
#include <hip/hip_runtime.h>
#include <hip/hip_bf16.h>

// DeltaNet block. B=2 L=4096 D=1024 H=8 DK=DV=128 KCONV=4 CHUNK=64
// Round 8: round-7 structure with the qbh aliasing fix (qbh -> h region 2nd half;
// it was clobbering qkv before conv_k/conv_v read it).
#define B_ 2
#define L_ 4096
#define D_ 1024
#define H_ 8
#define DK_ 128
#define NR_ (B_*L_)      // 8192 rows
#define NC_ 64           // chunks per sequence
#define CS_ 64           // chunk size

typedef __attribute__((ext_vector_type(8))) short short8;
typedef __attribute__((ext_vector_type(4))) float f32x4;

__device__ __forceinline__ float sigmf(float x){ return 1.0f/(1.0f+__expf(-x)); }
__device__ __forceinline__ float siluf(float x){ return x/(1.0f+__expf(-x)); }
__device__ __forceinline__ unsigned short f2bf(float f){
  __hip_bfloat16 h = __float2bfloat16(f);
  return *reinterpret_cast<unsigned short*>(&h);
}
__device__ __forceinline__ void gll16(const void* g, void* l){
  __builtin_amdgcn_global_load_lds((const __attribute__((address_space(1))) void*)g,
      (__attribute__((address_space(3))) void*)l, 16, 0, 0);
}

// ---------- RMSNorm over D, dual f32 + bf16 output ----------
__global__ __launch_bounds__(256) void rmsnorm_kernel(const float* __restrict__ x,
    const float* __restrict__ w, float* __restrict__ h, unsigned short* __restrict__ hb){
  int n = blockIdx.x; int t = threadIdx.x;
  float4 v = ((const float4*)(x + (size_t)n*D_))[t];
  float ss = v.x*v.x + v.y*v.y + v.z*v.z + v.w*v.w;
  #pragma unroll
  for (int m=32;m>0;m>>=1) ss += __shfl_xor(ss, m, 64);
  __shared__ float red[4];
  if ((t&63)==0) red[t>>6] = ss;
  __syncthreads();
  ss = red[0]+red[1]+red[2]+red[3];
  float rs = rsqrtf(ss*(1.0f/D_) + 1e-6f);
  float4 wv = ((const float4*)w)[t];
  float4 o; o.x=v.x*rs*wv.x; o.y=v.y*rs*wv.y; o.z=v.z*rs*wv.z; o.w=v.w*rs*wv.w;
  ((float4*)(h + (size_t)n*D_))[t] = o;
  ushort4 ob4; ob4.x=f2bf(o.x); ob4.y=f2bf(o.y); ob4.z=f2bf(o.z); ob4.w=f2bf(o.w);
  ((ushort4*)(hb + (size_t)n*D_))[t] = ob4;
}

// ---------- transpose + f32->bf16: W[1024][1024] -> Wt[n][k] ----------
__global__ __launch_bounds__(256) void transpose_bf16_kernel(const float* __restrict__ W,
    unsigned short* __restrict__ Wt){
  __shared__ float tile[64][65];
  int bi = blockIdx.y, bj = blockIdx.x;
  int tx = threadIdx.x & 63, tg = threadIdx.x >> 6;
  #pragma unroll
  for (int i=0;i<16;i++){
    int r = tg*16 + i;
    tile[r][tx] = W[(size_t)(bi*64 + r)*D_ + bj*64 + tx];
  }
  __syncthreads();
  #pragma unroll
  for (int i=0;i<16;i++){
    int r = tg*16 + i;
    Wt[(size_t)(bj*64 + r)*D_ + bi*64 + tx] = f2bf(tile[tx][r]);
  }
}

// ---------- bf16 MFMA GEMM: C[M,N] f32 = A[M,K]bf16 @ Bt[N,K]bf16^T (+R) ----------
__global__ __launch_bounds__(256) void gemm_bf16(const unsigned short* __restrict__ A,
    const unsigned short* __restrict__ Bt, const float* __restrict__ R,
    float* __restrict__ C, int N, int K){
  __shared__ __align__(16) unsigned short Al[4096];
  __shared__ __align__(16) unsigned short Bl[4096];
  int t = threadIdx.x, w = t>>6, l = t&63;
  int wm = w&1, wn = w>>1;
  int row0 = blockIdx.y*128, col0 = blockIdx.x*128;
  int lr = l&15, lk = l>>4;
  const unsigned short* ga0 = A  + (size_t)(row0 + w*16     + lr)*K + lk*8;
  const unsigned short* ga1 = A  + (size_t)(row0 + (w+4)*16 + lr)*K + lk*8;
  const unsigned short* gb0 = Bt + (size_t)(col0 + w*16     + lr)*K + lk*8;
  const unsigned short* gb1 = Bt + (size_t)(col0 + (w+4)*16 + lr)*K + lk*8;
  unsigned short* la0 = &Al[(w*64 + l)*8];
  unsigned short* la1 = &Al[((w+4)*64 + l)*8];
  unsigned short* lb0 = &Bl[(w*64 + l)*8];
  unsigned short* lb1 = &Bl[((w+4)*64 + l)*8];
  f32x4 acc[4][4];
  #pragma unroll
  for (int i=0;i<4;i++)
    #pragma unroll
    for (int j=0;j<4;j++) acc[i][j] = (f32x4){0.f,0.f,0.f,0.f};
  for (int k0=0;k0<K;k0+=32){
    gll16(ga0 + k0, la0);
    gll16(ga1 + k0, la1);
    gll16(gb0 + k0, lb0);
    gll16(gb1 + k0, lb1);
    __syncthreads();
    short8 af[4], bfr[4];
    #pragma unroll
    for (int i=0;i<4;i++) af[i]  = *(const short8*)&Al[((wm*4+i)*64 + l)*8];
    #pragma unroll
    for (int j=0;j<4;j++) bfr[j] = *(const short8*)&Bl[((wn*4+j)*64 + l)*8];
    #pragma unroll
    for (int i=0;i<4;i++)
      #pragma unroll
      for (int j=0;j<4;j++)
        acc[i][j] = __builtin_amdgcn_mfma_f32_16x16x32_bf16(af[i], bfr[j], acc[i][j], 0,0,0);
    __syncthreads();
  }
  int orow = row0 + wm*64 + (l>>4)*4;
  int ocol = col0 + wn*64 + (l&15);
  #pragma unroll
  for (int i=0;i<4;i++){
    #pragma unroll
    for (int j=0;j<4;j++){
      #pragma unroll
      for (int r=0;r<4;r++){
        size_t idx = (size_t)(orow + i*16 + r)*N + ocol + j*16;
        float res = R ? R[idx] : 0.0f;
        C[idx] = acc[i][j][r] + res;
      }
    }
  }
}

// ---------- beta = sigmoid(h @ Wb[1024,8]) ----------
__global__ __launch_bounds__(256) void beta_kernel(const float* __restrict__ h,
    const float* __restrict__ Wb, float* __restrict__ beta){
  int n = blockIdx.x, t = threadIdx.x;
  const float* hr = h + (size_t)n*D_;
  float p[8] = {};
  for (int kx=t; kx<D_; kx+=256){
    float hv = hr[kx];
    const float* wr = Wb + (size_t)kx*H_;
    #pragma unroll
    for (int j=0;j<8;j++) p[j] += hv*wr[j];
  }
  #pragma unroll
  for (int m=32;m>0;m>>=1){
    #pragma unroll
    for (int j=0;j<8;j++) p[j] += __shfl_xor(p[j], m, 64);
  }
  __shared__ float red[4][8];
  if ((t&63)==0){
    #pragma unroll
    for (int j=0;j<8;j++) red[t>>6][j] = p[j];
  }
  __syncthreads();
  if (t < 8){
    float s = red[0][t]+red[1][t]+red[2][t]+red[3][t];
    beta[(size_t)n*H_ + t] = sigmf(s);
  }
}

// ---------- causal depthwise conv(K=4) + silu; strided input (fused qkv) ----------
__global__ __launch_bounds__(256) void conv_silu_kernel(const float* __restrict__ in,
    const float* __restrict__ w, float* __restrict__ out, int ld){
  size_t idx = (size_t)blockIdx.x*256 + threadIdx.x;
  int c = (int)(idx & (D_-1));
  int n = (int)(idx >> 10);
  int l = n & (L_-1);
  const float* src = in + (size_t)n*ld + c;
  float4 wv = ((const float4*)w)[c];
  float acc = wv.w * src[0];
  if (l >= 1) acc += wv.z * src[-ld];
  if (l >= 2) acc += wv.y * src[-2*ld];
  if (l >= 3) acc += wv.x * src[-3*ld];
  out[(size_t)n*D_ + c] = siluf(acc);
}

// ---------- fused conv+silu then silu+l2norm per head (q,k paths) ----------
__global__ __launch_bounds__(256) void conv_silu_l2norm_kernel(const float* __restrict__ in,
    const float* __restrict__ w, float* __restrict__ outf, unsigned short* __restrict__ ob,
    float scale, int ld){
  int n = blockIdx.x, t = threadIdx.x;
  int c0 = t*4;
  int l = n & (L_-1);
  const float* src = in + (size_t)n*ld + c0;
  float4 x0 = *(const float4*)&src[0];
  float4 x1 = (l>=1) ? *(const float4*)&src[-ld]   : (float4){0,0,0,0};
  float4 x2 = (l>=2) ? *(const float4*)&src[-2*ld] : (float4){0,0,0,0};
  float4 x3 = (l>=3) ? *(const float4*)&src[-3*ld] : (float4){0,0,0,0};
  float4 w0 = ((const float4*)w)[c0+0];
  float4 w1 = ((const float4*)w)[c0+1];
  float4 w2 = ((const float4*)w)[c0+2];
  float4 w3 = ((const float4*)w)[c0+3];
  float4 u;
  u.x = siluf(w0.w*x0.x + w0.z*x1.x + w0.y*x2.x + w0.x*x3.x);
  u.y = siluf(w1.w*x0.y + w1.z*x1.y + w1.y*x2.y + w1.x*x3.y);
  u.z = siluf(w2.w*x0.z + w2.z*x1.z + w2.y*x2.z + w2.x*x3.z);
  u.w = siluf(w3.w*x0.w + w3.z*x1.w + w3.y*x2.w + w3.x*x3.w);
  u.x = siluf(u.x); u.y = siluf(u.y); u.z = siluf(u.z); u.w = siluf(u.w);
  float ss = u.x*u.x+u.y*u.y+u.z*u.z+u.w*u.w;
  #pragma unroll
  for (int m=16;m>0;m>>=1) ss += __shfl_xor(ss, m, 64);
  float rs = rsqrtf(ss + 1e-6f) * scale;
  u.x*=rs; u.y*=rs; u.z*=rs; u.w*=rs;
  ((float4*)(outf + (size_t)n*D_))[t] = u;
  if (ob){
    ushort4 r4; r4.x=f2bf(u.x); r4.y=f2bf(u.y); r4.z=f2bf(u.z); r4.w=f2bf(u.w);
    ((ushort4*)(ob + (size_t)n*D_))[t] = r4;
  }
}

// ---------- chunk-local: w=-A^-1(bk) [bf16], u=A^-1(bv) [f32], qk masked [bf16], kt=K^T [bf16] ----------
__global__ __launch_bounds__(256) void chunk_local_kernel(
    const float* __restrict__ q, const float* __restrict__ k, const float* __restrict__ v,
    const float* __restrict__ beta, unsigned short* __restrict__ wneg_buf,
    float* __restrict__ u_buf, unsigned short* __restrict__ qk_buf,
    unsigned short* __restrict__ kt_buf){
  int ci = blockIdx.x, bh = blockIdx.y;
  int b = bh >> 3, hh = bh & 7;
  int n0 = b*L_ + ci*CS_;
  int cbase = hh*DK_;
  int cid = bh*NC_ + ci;
  __shared__ float Ks[64][132];
  __shared__ float Als[64*68];
  __shared__ float rowW[144];
  __shared__ float rowU[144];
  __shared__ float bs[64];
  int t = threadIdx.x;
  {
    int r = t >> 2, c0 = (t & 3)*32;
    const float* kr = k + (size_t)(n0+r)*D_ + cbase + c0;
    #pragma unroll
    for (int m=0;m<32;m+=4) *(float4*)&Ks[r][c0+m] = *(const float4*)&kr[m];
  }
  if (t < 64) bs[t] = beta[(size_t)(n0+t)*H_ + hh];
  __syncthreads();
  int ti = t >> 4, tj = t & 15;
  {
    float cc[4][4] = {};
    #pragma unroll 2
    for (int d=0; d<128; d+=4){
      float4 ar[4], br[4];
      #pragma unroll
      for (int r2=0;r2<4;r2++) ar[r2] = *(const float4*)&Ks[ti+16*r2][d];
      #pragma unroll
      for (int s2=0;s2<4;s2++) br[s2] = *(const float4*)&Ks[tj+16*s2][d];
      #pragma unroll
      for (int r2=0;r2<4;r2++){
        #pragma unroll
        for (int s2=0;s2<4;s2++){
          cc[r2][s2] += ar[r2].x*br[s2].x + ar[r2].y*br[s2].y
                      + ar[r2].z*br[s2].z + ar[r2].w*br[s2].w;
        }
      }
    }
    #pragma unroll
    for (int r2=0;r2<4;r2++){
      #pragma unroll
      for (int s2=0;s2<4;s2++){
        int i2 = ti + 16*r2, j2 = tj + 16*s2;
        Als[i2*68 + j2] = (j2 < i2) ? bs[i2]*cc[r2][s2] : 0.0f;
      }
    }
  }
  __syncthreads();
  int i = t >> 2, part = t & 3, ds = part*32, dp = part*36;
  float wreg[32], ureg[32];
  {
    float bi = bs[i];
    const float* vr = v + (size_t)(n0+i)*D_ + cbase + ds;
    #pragma unroll
    for (int m=0;m<32;m++) wreg[m] = bi * Ks[i][ds+m];
    #pragma unroll
    for (int m=0;m<32;m+=4){
      float4 vv = *(const float4*)&vr[m];
      ureg[m+0]=bi*vv.x; ureg[m+1]=bi*vv.y; ureg[m+2]=bi*vv.z; ureg[m+3]=bi*vv.w;
    }
  }
  for (int j=0;j<63;j++){
    if (i == j){
      #pragma unroll
      for (int m=0;m<32;m++){ rowW[dp+m]=wreg[m]; rowU[dp+m]=ureg[m]; }
    }
    __syncthreads();
    if (i > j){
      float aj = Als[i*68 + j];
      #pragma unroll
      for (int m=0;m<32;m++){ wreg[m] -= aj*rowW[dp+m]; ureg[m] -= aj*rowU[dp+m]; }
    }
    __syncthreads();
  }
  {
    unsigned short* wd = wneg_buf + (size_t)cid*(64*128) + (size_t)i*128 + ds;
    float* ud = u_buf + (size_t)cid*(64*128) + (size_t)i*128 + ds;
    #pragma unroll
    for (int m=0;m<32;m+=4){
      ushort4 f; f.x=f2bf(-wreg[m]); f.y=f2bf(-wreg[m+1]); f.z=f2bf(-wreg[m+2]); f.w=f2bf(-wreg[m+3]);
      *(ushort4*)&wd[m] = f;
      float4 g; g.x=ureg[m]; g.y=ureg[m+1]; g.z=ureg[m+2]; g.w=ureg[m+3];
      *(float4*)&ud[m] = g;
    }
  }
  __syncthreads();
  {
    const float* qbase = q + (size_t)n0*D_ + cbase;
    float cc[4][4] = {};
    #pragma unroll 2
    for (int d=0; d<128; d+=4){
      float4 ar[4], br[4];
      #pragma unroll
      for (int r2=0;r2<4;r2++) ar[r2] = *(const float4*)&qbase[(size_t)(ti+16*r2)*D_ + d];
      #pragma unroll
      for (int s2=0;s2<4;s2++) br[s2] = *(const float4*)&Ks[tj+16*s2][d];
      #pragma unroll
      for (int r2=0;r2<4;r2++){
        #pragma unroll
        for (int s2=0;s2<4;s2++){
          cc[r2][s2] += ar[r2].x*br[s2].x + ar[r2].y*br[s2].y
                      + ar[r2].z*br[s2].z + ar[r2].w*br[s2].w;
        }
      }
    }
    unsigned short* qkd = qk_buf + (size_t)cid*4096;
    #pragma unroll
    for (int r2=0;r2<4;r2++){
      #pragma unroll
      for (int s2=0;s2<4;s2++){
        int i2 = ti+16*r2, j2 = tj+16*s2;
        qkd[i2*64 + j2] = (j2 <= i2) ? f2bf(cc[r2][s2]) : (unsigned short)0;
      }
    }
  }
  {
    unsigned short* ktd = kt_buf + (size_t)cid*(64*128);
    for (int idx = t; idx < 8192; idx += 256){
      int d = idx >> 6, i2 = idx & 63;
      ktd[idx] = f2bf(Ks[i2][d]);
    }
  }
}

// ---------- MFMA seq scan v3: 512 thr / 8 waves, dbuf S mirror, 2 barriers/step ----------
__global__ __launch_bounds__(512) void seq_kernel(
    const unsigned short* __restrict__ wneg_buf, const float* __restrict__ u_buf,
    const unsigned short* __restrict__ kt_buf, const unsigned short* __restrict__ qk_buf,
    const unsigned short* __restrict__ qbh, float* __restrict__ o_buf){
  int bid = blockIdx.x;
  int bh = bid & 15, cg = bid >> 4;
  int b = bh >> 3, hh = bh & 7;
  int cbase = hh*DK_;
  int t = threadIdx.x;
  int w = t >> 6, l = t & 63, g = l >> 4, lr = l & 15;
  int mt = w >> 1, nt = w & 1;        // B/C tile ownership
  int ct = w >> 2, dtp = (w & 3)*2;   // D tile ownership (2 d-tiles)

  __shared__ __align__(16) unsigned short Wl[2][8192];
  __shared__ __align__(16) unsigned short Ql[2][8192];
  __shared__ __align__(16) unsigned short Ktl[2][8192];
  __shared__ __align__(16) unsigned short qkl[2][4096];
  __shared__ __align__(16) float  Ul[2][2048];
  __shared__ __align__(16) unsigned short Stl[2][32*136]; // S^T bf16, double-buffered
  __shared__ __align__(16) unsigned short vTl[32*72];     // v_new^T bf16

  f32x4 Sacc[2];
  Sacc[0] = (f32x4){0.f,0.f,0.f,0.f};
  Sacc[1] = (f32x4){0.f,0.f,0.f,0.f};

  for (int z=t; z<2*32*136; z+=512) ((unsigned short*)Stl)[z] = 0;

  size_t cid0 = (size_t)bh*NC_;
  const unsigned short* wb_  = wneg_buf + cid0*8192;
  const unsigned short* ktb_ = kt_buf  + cid0*8192;
  const unsigned short* qkb_ = qk_buf  + cid0*4096;
  const float*          ub_  = u_buf   + cid0*8192;
  const unsigned short* qb_  = qbh + (size_t)(b*L_)*D_ + cbase;

  int offW[2], offQ[2], offK[2];
  #pragma unroll
  for (int r=0;r<2;r++){
    int u = r*512 + t;
    int fm = u>>8, kq = (u>>6)&3, ll = u&63;
    offW[r] = (16*fm + (ll&15))*128 + kq*32 + (ll>>4)*8;
    offQ[r] = (16*fm + (ll&15))*D_  + kq*32 + (ll>>4)*8;
    int fn = u>>7, kqk = (u>>6)&1;
    offK[r] = (16*fn + (ll&15))*64 + kqk*32 + (ll>>4)*8;
  }
  int offQk, offU;
  {
    int u = t;
    int fm = u>>7, kq = (u>>6)&1, ll = u&63;
    offQk = (16*fm + (ll&15))*64 + kq*32 + (ll>>4)*8;
    offU  = (u>>3)*128 + cg*32 + (u&7)*4;
  }

  #define STAGE(BI, CI) do { \
    const unsigned short* wp  = wb_  + (size_t)(CI)*8192; \
    const unsigned short* kp  = ktb_ + (size_t)(CI)*8192; \
    const unsigned short* qkp = qkb_ + (size_t)(CI)*4096; \
    const float*          up  = ub_  + (size_t)(CI)*8192; \
    const unsigned short* qp  = qb_  + (size_t)(CI)*CS_*D_; \
    _Pragma("unroll") \
    for (int r=0;r<2;r++){ \
      gll16(wp + offW[r], &Wl[BI][(r*512+t)*8]); \
      gll16(qp + offQ[r], &Ql[BI][(r*512+t)*8]); \
      gll16(kp + offK[r], &Ktl[BI][(r*512+t)*8]); \
    } \
    gll16(qkp + offQk, &qkl[BI][t*8]); \
    gll16(up + offU, &Ul[BI][t*4]); \
  } while(0)

  STAGE(0, 0);
  asm volatile("s_waitcnt vmcnt(0) lgkmcnt(0)" ::: "memory");
  __builtin_amdgcn_s_barrier();
  __builtin_amdgcn_sched_barrier(0);

  int cur = 0;
  for (int ci=0; ci<NC_; ++ci){
    int cn = (ci+1 < NC_) ? ci+1 : ci;
    STAGE(cur^1, cn);   // prefetch next chunk; stays in flight across both barriers

    // ---- phase B: v_new = U + (-W)@S_prev ----
    f32x4 accV;
    #pragma unroll
    for (int r=0;r<4;r++) accV[r] = Ul[cur][(16*mt + 4*g + r)*32 + 16*nt + lr];
    #pragma unroll
    for (int kq=0;kq<4;kq++){
      short8 a  = *(const short8*)&Wl[cur][(mt*4+kq)*512 + l*8];
      short8 b0 = *(const short8*)&Stl[cur][(16*nt + lr)*136 + kq*32 + g*8];
      accV = __builtin_amdgcn_mfma_f32_16x16x32_bf16(a, b0, accV, 0,0,0);
    }
    #pragma unroll
    for (int r=0;r<4;r++)
      vTl[(16*nt + lr)*72 + 16*mt + 4*g + r] = f2bf(accV[r]);
    asm volatile("s_waitcnt lgkmcnt(0)" ::: "memory");
    __builtin_amdgcn_s_barrier();
    __builtin_amdgcn_sched_barrier(0);

    // ---- phase CD: D (S update, regs) + C (o out); C reads Stl[cur], D writes Stl[cur^1] ----
    #pragma unroll
    for (int kq=0;kq<2;kq++){
      short8 aD = *(const short8*)&vTl[(16*ct + lr)*72 + kq*32 + g*8];
      short8 bD0 = *(const short8*)&Ktl[cur][((dtp+0)*2 + kq)*512 + l*8];
      short8 bD1 = *(const short8*)&Ktl[cur][((dtp+1)*2 + kq)*512 + l*8];
      Sacc[0] = __builtin_amdgcn_mfma_f32_16x16x32_bf16(aD, bD0, Sacc[0], 0,0,0);
      Sacc[1] = __builtin_amdgcn_mfma_f32_16x16x32_bf16(aD, bD1, Sacc[1], 0,0,0);
    }
    f32x4 accO = (f32x4){0.f,0.f,0.f,0.f};
    #pragma unroll
    for (int kq=0;kq<4;kq++){
      short8 a  = *(const short8*)&Ql[cur][(mt*4+kq)*512 + l*8];
      short8 b0 = *(const short8*)&Stl[cur][(16*nt + lr)*136 + kq*32 + g*8];
      accO = __builtin_amdgcn_mfma_f32_16x16x32_bf16(a, b0, accO, 0,0,0);
    }
    #pragma unroll
    for (int kq=0;kq<2;kq++){
      short8 a  = *(const short8*)&qkl[cur][(mt*2+kq)*512 + l*8];
      short8 b0 = *(const short8*)&vTl[(16*nt + lr)*72 + kq*32 + g*8];
      accO = __builtin_amdgcn_mfma_f32_16x16x32_bf16(a, b0, accO, 0,0,0);
    }
    #pragma unroll
    for (int j=0;j<2;j++){
      #pragma unroll
      for (int r=0;r<4;r++)
        Stl[cur^1][(16*ct + 4*g + r)*136 + 16*(dtp+j) + lr] = f2bf(Sacc[j][r]);
    }
    {
      int n0 = b*L_ + ci*CS_;
      #pragma unroll
      for (int r=0;r<4;r++)
        o_buf[(size_t)(n0 + 16*mt + 4*g + r)*D_ + cbase + cg*32 + 16*nt + lr] = accO[r];
    }
    asm volatile("s_waitcnt lgkmcnt(0)" ::: "memory");
    asm volatile("s_waitcnt vmcnt(4)" ::: "memory");  // 8 prefetch loads retired; 4 o-stores fly
    __builtin_amdgcn_s_barrier();
    __builtin_amdgcn_sched_barrier(0);
    cur ^= 1;
  }
  #undef STAGE
}

// ---------- per-head RMSNorm over DV=128, bf16 out ----------
__global__ __launch_bounds__(256) void head_rmsnorm_kernel(const float* __restrict__ o,
    const float* __restrict__ w, unsigned short* __restrict__ out){
  int n = blockIdx.x, t = threadIdx.x;
  float4 v = ((const float4*)(o + (size_t)n*D_))[t];
  float ss = v.x*v.x+v.y*v.y+v.z*v.z+v.w*v.w;
  #pragma unroll
  for (int m=16;m>0;m>>=1) ss += __shfl_xor(ss, m, 64);
  float rs = rsqrtf(ss*(1.0f/DK_) + 1e-6f);
  float4 wv = ((const float4*)w)[t & 31];
  float4 u; u.x=v.x*rs*wv.x; u.y=v.y*rs*wv.y; u.z=v.z*rs*wv.z; u.w=v.w*rs*wv.w;
  ushort4 r4; r4.x=f2bf(u.x); r4.y=f2bf(u.y); r4.z=f2bf(u.z); r4.w=f2bf(u.w);
  ((ushort4*)(out + (size_t)n*D_))[t] = r4;
}

extern "C" void kernel_launch(void* const* d_in, const int* in_sizes, int n_in,
                              void* d_out, int out_size, void* d_ws, size_t ws_size,
                              hipStream_t stream){
  const float* x      = (const float*)d_in[0];
  const float* norm_w = (const float*)d_in[1];
  const float* Wq     = (const float*)d_in[2];
  const float* Wk     = (const float*)d_in[3];
  const float* Wv     = (const float*)d_in[4];
  const float* Wb     = (const float*)d_in[5];
  const float* conv_q = (const float*)d_in[6];
  const float* conv_k = (const float*)d_in[7];
  const float* conv_v = (const float*)d_in[8];
  const float* onw    = (const float*)d_in[9];
  const float* Wo     = (const float*)d_in[10];
  float* out = (float*)d_out;

  const size_t NB = (size_t)NR_*D_;           // 8,388,608 floats
  float* ws   = (float*)d_ws;
  float* h    = ws;                 // f32 h; halves later reused: [0,NB/2)=obb, [NB/2,NB)=qbh
  float* qkv  = ws + NB;            // fused [8192][3072] f32; later recurrence buffers
  float* qb   = ws + 4*NB;          // hb (bf16) aliases here until fused conv writes qb
  float* kb   = ws + 5*NB;
  float* vb   = ws + 6*NB;          // v f32 -> o f32 (seq output)
  float* betab= ws + 7*NB;          // 65536 floats
  unsigned short* wtq = (unsigned short*)(betab + 65536);
  unsigned short* wtk = wtq + (size_t)D_*D_;
  unsigned short* wtv = wtk + (size_t)D_*D_;
  unsigned short* wto = wtv + (size_t)D_*D_;
  unsigned short* hb  = (unsigned short*)qb;
  unsigned short* obb = (unsigned short*)h;             // h[0 .. NB/2) region
  unsigned short* qbh = (unsigned short*)(h + NB/2);    // h[NB/2 .. NB): dead after beta_kernel
  // recurrence buffers inside dead qkv region (72MB <= 100.66MB):
  unsigned short* wneg = (unsigned short*)qkv;             // 16MB
  unsigned short* ktb  = wneg + (size_t)8*1024*1024;       // 16MB
  unsigned short* qkbf = ktb  + (size_t)8*1024*1024;       // 8MB
  float*          ubuf = (float*)(qkbf + (size_t)4*1024*1024); // 32MB

  rmsnorm_kernel<<<NR_, 256, 0, stream>>>(x, norm_w, h, hb);
  dim3 tg(16,16);
  transpose_bf16_kernel<<<tg, 256, 0, stream>>>(Wq, wtq);
  transpose_bf16_kernel<<<tg, 256, 0, stream>>>(Wk, wtk);
  transpose_bf16_kernel<<<tg, 256, 0, stream>>>(Wv, wtv);
  transpose_bf16_kernel<<<tg, 256, 0, stream>>>(Wo, wto);
  // fused QKV projection: N = 3072
  dim3 gq(3*D_/128, NR_/128);   // (24, 64)
  gemm_bf16<<<gq, 256, 0, stream>>>(hb, wtq, nullptr, qkv, 3*D_, D_);
  beta_kernel<<<NR_, 256, 0, stream>>>(h, Wb, betab);   // last reader of h f32
  const float qscale = 0.08838834764831845f;  // DK^-0.5
  conv_silu_l2norm_kernel<<<NR_, 256, 0, stream>>>(qkv,      conv_q, qb, qbh, qscale, 3*D_);
  conv_silu_l2norm_kernel<<<NR_, 256, 0, stream>>>(qkv + D_, conv_k, kb, nullptr, 1.0f, 3*D_);
  conv_silu_kernel<<<(int)(NB/256), 256, 0, stream>>>(qkv + 2*D_, conv_v, vb, 3*D_);
  chunk_local_kernel<<<dim3(NC_, 16), 256, 0, stream>>>(qb, kb, vb, betab,
      wneg, ubuf, qkbf, ktb);
  seq_kernel<<<64, 512, 0, stream>>>(wneg, ubuf, ktb, qkbf, qbh, vb);
  head_rmsnorm_kernel<<<NR_, 256, 0, stream>>>(vb, onw, obb);
  dim3 gg(D_/128, NR_/128);
  gemm_bf16<<<gg, 256, 0, stream>>>(obb, wto, x, out, D_, D_);
  (void)in_sizes; (void)n_in; (void)out_size; (void)ws_size;
}

// Round 10
// 682.451 us; speedup vs baseline: 2.8985x; 1.0090x over previous
//
#include <hip/hip_runtime.h>
#include <hip/hip_bf16.h>

// DeltaNet block. B=2 L=4096 D=1024 H=8 DK=DV=128 KCONV=4 CHUNK=64
// Round 9 (resubmit): GEMM v2 (double-buffered 2-phase, 1 barrier/K-step, overlapped
// staging); beta fused into rmsnorm (h f32 dropped); 4 transposes merged into 1 launch.
#define B_ 2
#define L_ 4096
#define D_ 1024
#define H_ 8
#define DK_ 128
#define NR_ (B_*L_)      // 8192 rows
#define NC_ 64           // chunks per sequence
#define CS_ 64           // chunk size

typedef __attribute__((ext_vector_type(8))) short short8;
typedef __attribute__((ext_vector_type(4))) float f32x4;

__device__ __forceinline__ float sigmf(float x){ return 1.0f/(1.0f+__expf(-x)); }
__device__ __forceinline__ float siluf(float x){ return x/(1.0f+__expf(-x)); }
__device__ __forceinline__ unsigned short f2bf(float f){
  __hip_bfloat16 h = __float2bfloat16(f);
  return *reinterpret_cast<unsigned short*>(&h);
}
__device__ __forceinline__ void gll16(const void* g, void* l){
  __builtin_amdgcn_global_load_lds((const __attribute__((address_space(1))) void*)g,
      (__attribute__((address_space(3))) void*)l, 16, 0, 0);
}

// ---------- RMSNorm over D (bf16 out) + fused beta = sigmoid(h@Wb) ----------
__global__ __launch_bounds__(256) void rmsnorm_beta_kernel(const float* __restrict__ x,
    const float* __restrict__ w, const float* __restrict__ Wb,
    unsigned short* __restrict__ hb, float* __restrict__ beta){
  int n = blockIdx.x; int t = threadIdx.x;
  float4 v = ((const float4*)(x + (size_t)n*D_))[t];
  float ss = v.x*v.x + v.y*v.y + v.z*v.z + v.w*v.w;
  #pragma unroll
  for (int m=32;m>0;m>>=1) ss += __shfl_xor(ss, m, 64);
  __shared__ float red[4];
  __shared__ float bred[4][8];
  if ((t&63)==0) red[t>>6] = ss;
  __syncthreads();
  ss = red[0]+red[1]+red[2]+red[3];
  float rs = rsqrtf(ss*(1.0f/D_) + 1e-6f);
  float4 wv = ((const float4*)w)[t];
  float4 o; o.x=v.x*rs*wv.x; o.y=v.y*rs*wv.y; o.z=v.z*rs*wv.z; o.w=v.w*rs*wv.w;
  ushort4 ob4; ob4.x=f2bf(o.x); ob4.y=f2bf(o.y); ob4.z=f2bf(o.z); ob4.w=f2bf(o.w);
  ((ushort4*)(hb + (size_t)n*D_))[t] = ob4;
  // beta: p[j] = sum_c h_c * Wb[c][j]
  float p[8];
  {
    const float* wb0 = Wb + (size_t)(t*4)*H_;
    float4 a0 = *(const float4*)&wb0[0],  a1 = *(const float4*)&wb0[4];
    float4 b0 = *(const float4*)&wb0[8],  b1 = *(const float4*)&wb0[12];
    float4 c0 = *(const float4*)&wb0[16], c1 = *(const float4*)&wb0[20];
    float4 d0 = *(const float4*)&wb0[24], d1 = *(const float4*)&wb0[28];
    p[0]=o.x*a0.x+o.y*b0.x+o.z*c0.x+o.w*d0.x;
    p[1]=o.x*a0.y+o.y*b0.y+o.z*c0.y+o.w*d0.y;
    p[2]=o.x*a0.z+o.y*b0.z+o.z*c0.z+o.w*d0.z;
    p[3]=o.x*a0.w+o.y*b0.w+o.z*c0.w+o.w*d0.w;
    p[4]=o.x*a1.x+o.y*b1.x+o.z*c1.x+o.w*d1.x;
    p[5]=o.x*a1.y+o.y*b1.y+o.z*c1.y+o.w*d1.y;
    p[6]=o.x*a1.z+o.y*b1.z+o.z*c1.z+o.w*d1.z;
    p[7]=o.x*a1.w+o.y*b1.w+o.z*c1.w+o.w*d1.w;
  }
  #pragma unroll
  for (int m=32;m>0;m>>=1){
    #pragma unroll
    for (int j=0;j<8;j++) p[j] += __shfl_xor(p[j], m, 64);
  }
  if ((t&63)==0){
    #pragma unroll
    for (int j=0;j<8;j++) bred[t>>6][j] = p[j];
  }
  __syncthreads();
  if (t < 8){
    float s = bred[0][t]+bred[1][t]+bred[2][t]+bred[3][t];
    beta[(size_t)n*H_ + t] = sigmf(s);
  }
}

// ---------- 4x transpose + f32->bf16: W[1024][1024] -> Wt[n][k] (z selects matrix) ----------
__global__ __launch_bounds__(256) void transpose4_bf16_kernel(const float* __restrict__ W0,
    const float* __restrict__ W1, const float* __restrict__ W2, const float* __restrict__ W3,
    unsigned short* __restrict__ Wt){
  __shared__ float tile[64][65];
  int z = blockIdx.z;
  const float* W = (z==0)?W0:(z==1)?W1:(z==2)?W2:W3;
  unsigned short* dst = Wt + (size_t)z*D_*D_;
  int bi = blockIdx.y, bj = blockIdx.x;
  int tx = threadIdx.x & 63, tg = threadIdx.x >> 6;
  #pragma unroll
  for (int i=0;i<16;i++){
    int r = tg*16 + i;
    tile[r][tx] = W[(size_t)(bi*64 + r)*D_ + bj*64 + tx];
  }
  __syncthreads();
  #pragma unroll
  for (int i=0;i<16;i++){
    int r = tg*16 + i;
    dst[(size_t)(bj*64 + r)*D_ + bi*64 + tx] = f2bf(tile[tx][r]);
  }
}

// ---------- bf16 MFMA GEMM v2: dbuf LDS, 1 barrier/K-step, overlapped staging ----------
__global__ __launch_bounds__(256) void gemm_bf16(const unsigned short* __restrict__ A,
    const unsigned short* __restrict__ Bt, const float* __restrict__ R,
    float* __restrict__ C, int N, int K){
  __shared__ __align__(16) unsigned short Al[2][4096];
  __shared__ __align__(16) unsigned short Bl[2][4096];
  int t = threadIdx.x, w = t>>6, l = t&63;
  int wm = w&1, wn = w>>1;
  int row0 = blockIdx.y*128, col0 = blockIdx.x*128;
  int lr = l&15, lk = l>>4;
  const unsigned short* ga0 = A  + (size_t)(row0 + w*16     + lr)*K + lk*8;
  const unsigned short* ga1 = A  + (size_t)(row0 + (w+4)*16 + lr)*K + lk*8;
  const unsigned short* gb0 = Bt + (size_t)(col0 + w*16     + lr)*K + lk*8;
  const unsigned short* gb1 = Bt + (size_t)(col0 + (w+4)*16 + lr)*K + lk*8;
  int dA0 = (w*64 + l)*8, dA1 = ((w+4)*64 + l)*8;
  f32x4 acc[4][4];
  #pragma unroll
  for (int i=0;i<4;i++)
    #pragma unroll
    for (int j=0;j<4;j++) acc[i][j] = (f32x4){0.f,0.f,0.f,0.f};

  #define GSTAGE(BI, KO) do { \
    gll16(ga0 + (KO), &Al[BI][dA0]); \
    gll16(ga1 + (KO), &Al[BI][dA1]); \
    gll16(gb0 + (KO), &Bl[BI][dA0]); \
    gll16(gb1 + (KO), &Bl[BI][dA1]); \
  } while(0)

  GSTAGE(0, 0);
  asm volatile("s_waitcnt vmcnt(0)" ::: "memory");
  __builtin_amdgcn_s_barrier();
  __builtin_amdgcn_sched_barrier(0);
  int nk = K >> 5, cur = 0;
  for (int k=0; k<nk; ++k){
    if (k+1 < nk) GSTAGE(cur^1, (k+1)*32);
    short8 af[4], bfr[4];
    #pragma unroll
    for (int i=0;i<4;i++) af[i]  = *(const short8*)&Al[cur][((wm*4+i)*64 + l)*8];
    #pragma unroll
    for (int j=0;j<4;j++) bfr[j] = *(const short8*)&Bl[cur][((wn*4+j)*64 + l)*8];
    #pragma unroll
    for (int i=0;i<4;i++)
      #pragma unroll
      for (int j=0;j<4;j++)
        acc[i][j] = __builtin_amdgcn_mfma_f32_16x16x32_bf16(af[i], bfr[j], acc[i][j], 0,0,0);
    asm volatile("s_waitcnt vmcnt(0)" ::: "memory");
    __builtin_amdgcn_s_barrier();
    __builtin_amdgcn_sched_barrier(0);
    cur ^= 1;
  }
  #undef GSTAGE
  int orow = row0 + wm*64 + (l>>4)*4;
  int ocol = col0 + wn*64 + (l&15);
  #pragma unroll
  for (int i=0;i<4;i++){
    #pragma unroll
    for (int j=0;j<4;j++){
      #pragma unroll
      for (int r=0;r<4;r++){
        size_t idx = (size_t)(orow + i*16 + r)*N + ocol + j*16;
        float res = R ? R[idx] : 0.0f;
        C[idx] = acc[i][j][r] + res;
      }
    }
  }
}

// ---------- causal depthwise conv(K=4) + silu; strided input (fused qkv) ----------
__global__ __launch_bounds__(256) void conv_silu_kernel(const float* __restrict__ in,
    const float* __restrict__ w, float* __restrict__ out, int ld){
  size_t idx = (size_t)blockIdx.x*256 + threadIdx.x;
  int c = (int)(idx & (D_-1));
  int n = (int)(idx >> 10);
  int l = n & (L_-1);
  const float* src = in + (size_t)n*ld + c;
  float4 wv = ((const float4*)w)[c];
  float acc = wv.w * src[0];
  if (l >= 1) acc += wv.z * src[-ld];
  if (l >= 2) acc += wv.y * src[-2*ld];
  if (l >= 3) acc += wv.x * src[-3*ld];
  out[(size_t)n*D_ + c] = siluf(acc);
}

// ---------- fused conv+silu then silu+l2norm per head (q,k paths) ----------
__global__ __launch_bounds__(256) void conv_silu_l2norm_kernel(const float* __restrict__ in,
    const float* __restrict__ w, float* __restrict__ outf, unsigned short* __restrict__ ob,
    float scale, int ld){
  int n = blockIdx.x, t = threadIdx.x;
  int c0 = t*4;
  int l = n & (L_-1);
  const float* src = in + (size_t)n*ld + c0;
  float4 x0 = *(const float4*)&src[0];
  float4 x1 = (l>=1) ? *(const float4*)&src[-ld]   : (float4){0,0,0,0};
  float4 x2 = (l>=2) ? *(const float4*)&src[-2*ld] : (float4){0,0,0,0};
  float4 x3 = (l>=3) ? *(const float4*)&src[-3*ld] : (float4){0,0,0,0};
  float4 w0 = ((const float4*)w)[c0+0];
  float4 w1 = ((const float4*)w)[c0+1];
  float4 w2 = ((const float4*)w)[c0+2];
  float4 w3 = ((const float4*)w)[c0+3];
  float4 u;
  u.x = siluf(w0.w*x0.x + w0.z*x1.x + w0.y*x2.x + w0.x*x3.x);
  u.y = siluf(w1.w*x0.y + w1.z*x1.y + w1.y*x2.y + w1.x*x3.y);
  u.z = siluf(w2.w*x0.z + w2.z*x1.z + w2.y*x2.z + w2.x*x3.z);
  u.w = siluf(w3.w*x0.w + w3.z*x1.w + w3.y*x2.w + w3.x*x3.w);
  u.x = siluf(u.x); u.y = siluf(u.y); u.z = siluf(u.z); u.w = siluf(u.w);
  float ss = u.x*u.x+u.y*u.y+u.z*u.z+u.w*u.w;
  #pragma unroll
  for (int m=16;m>0;m>>=1) ss += __shfl_xor(ss, m, 64);
  float rs = rsqrtf(ss + 1e-6f) * scale;
  u.x*=rs; u.y*=rs; u.z*=rs; u.w*=rs;
  ((float4*)(outf + (size_t)n*D_))[t] = u;
  if (ob){
    ushort4 r4; r4.x=f2bf(u.x); r4.y=f2bf(u.y); r4.z=f2bf(u.z); r4.w=f2bf(u.w);
    ((ushort4*)(ob + (size_t)n*D_))[t] = r4;
  }
}

// ---------- chunk-local: w=-A^-1(bk) [bf16], u=A^-1(bv) [f32], qk masked [bf16], kt=K^T [bf16] ----------
__global__ __launch_bounds__(256) void chunk_local_kernel(
    const float* __restrict__ q, const float* __restrict__ k, const float* __restrict__ v,
    const float* __restrict__ beta, unsigned short* __restrict__ wneg_buf,
    float* __restrict__ u_buf, unsigned short* __restrict__ qk_buf,
    unsigned short* __restrict__ kt_buf){
  int ci = blockIdx.x, bh = blockIdx.y;
  int b = bh >> 3, hh = bh & 7;
  int n0 = b*L_ + ci*CS_;
  int cbase = hh*DK_;
  int cid = bh*NC_ + ci;
  __shared__ float Ks[64][132];
  __shared__ float Als[64*68];
  __shared__ float rowW[144];
  __shared__ float rowU[144];
  __shared__ float bs[64];
  int t = threadIdx.x;
  {
    int r = t >> 2, c0 = (t & 3)*32;
    const float* kr = k + (size_t)(n0+r)*D_ + cbase + c0;
    #pragma unroll
    for (int m=0;m<32;m+=4) *(float4*)&Ks[r][c0+m] = *(const float4*)&kr[m];
  }
  if (t < 64) bs[t] = beta[(size_t)(n0+t)*H_ + hh];
  __syncthreads();
  int ti = t >> 4, tj = t & 15;
  {
    float cc[4][4] = {};
    #pragma unroll 2
    for (int d=0; d<128; d+=4){
      float4 ar[4], br[4];
      #pragma unroll
      for (int r2=0;r2<4;r2++) ar[r2] = *(const float4*)&Ks[ti+16*r2][d];
      #pragma unroll
      for (int s2=0;s2<4;s2++) br[s2] = *(const float4*)&Ks[tj+16*s2][d];
      #pragma unroll
      for (int r2=0;r2<4;r2++){
        #pragma unroll
        for (int s2=0;s2<4;s2++){
          cc[r2][s2] += ar[r2].x*br[s2].x + ar[r2].y*br[s2].y
                      + ar[r2].z*br[s2].z + ar[r2].w*br[s2].w;
        }
      }
    }
    #pragma unroll
    for (int r2=0;r2<4;r2++){
      #pragma unroll
      for (int s2=0;s2<4;s2++){
        int i2 = ti + 16*r2, j2 = tj + 16*s2;
        Als[i2*68 + j2] = (j2 < i2) ? bs[i2]*cc[r2][s2] : 0.0f;
      }
    }
  }
  __syncthreads();
  int i = t >> 2, part = t & 3, ds = part*32, dp = part*36;
  float wreg[32], ureg[32];
  {
    float bi = bs[i];
    const float* vr = v + (size_t)(n0+i)*D_ + cbase + ds;
    #pragma unroll
    for (int m=0;m<32;m++) wreg[m] = bi * Ks[i][ds+m];
    #pragma unroll
    for (int m=0;m<32;m+=4){
      float4 vv = *(const float4*)&vr[m];
      ureg[m+0]=bi*vv.x; ureg[m+1]=bi*vv.y; ureg[m+2]=bi*vv.z; ureg[m+3]=bi*vv.w;
    }
  }
  for (int j=0;j<63;j++){
    if (i == j){
      #pragma unroll
      for (int m=0;m<32;m++){ rowW[dp+m]=wreg[m]; rowU[dp+m]=ureg[m]; }
    }
    __syncthreads();
    if (i > j){
      float aj = Als[i*68 + j];
      #pragma unroll
      for (int m=0;m<32;m++){ wreg[m] -= aj*rowW[dp+m]; ureg[m] -= aj*rowU[dp+m]; }
    }
    __syncthreads();
  }
  {
    unsigned short* wd = wneg_buf + (size_t)cid*(64*128) + (size_t)i*128 + ds;
    float* ud = u_buf + (size_t)cid*(64*128) + (size_t)i*128 + ds;
    #pragma unroll
    for (int m=0;m<32;m+=4){
      ushort4 f; f.x=f2bf(-wreg[m]); f.y=f2bf(-wreg[m+1]); f.z=f2bf(-wreg[m+2]); f.w=f2bf(-wreg[m+3]);
      *(ushort4*)&wd[m] = f;
      float4 g; g.x=ureg[m]; g.y=ureg[m+1]; g.z=ureg[m+2]; g.w=ureg[m+3];
      *(float4*)&ud[m] = g;
    }
  }
  __syncthreads();
  {
    const float* qbase = q + (size_t)n0*D_ + cbase;
    float cc[4][4] = {};
    #pragma unroll 2
    for (int d=0; d<128; d+=4){
      float4 ar[4], br[4];
      #pragma unroll
      for (int r2=0;r2<4;r2++) ar[r2] = *(const float4*)&qbase[(size_t)(ti+16*r2)*D_ + d];
      #pragma unroll
      for (int s2=0;s2<4;s2++) br[s2] = *(const float4*)&Ks[tj+16*s2][d];
      #pragma unroll
      for (int r2=0;r2<4;r2++){
        #pragma unroll
        for (int s2=0;s2<4;s2++){
          cc[r2][s2] += ar[r2].x*br[s2].x + ar[r2].y*br[s2].y
                      + ar[r2].z*br[s2].z + ar[r2].w*br[s2].w;
        }
      }
    }
    unsigned short* qkd = qk_buf + (size_t)cid*4096;
    #pragma unroll
    for (int r2=0;r2<4;r2++){
      #pragma unroll
      for (int s2=0;s2<4;s2++){
        int i2 = ti+16*r2, j2 = tj+16*s2;
        qkd[i2*64 + j2] = (j2 <= i2) ? f2bf(cc[r2][s2]) : (unsigned short)0;
      }
    }
  }
  {
    unsigned short* ktd = kt_buf + (size_t)cid*(64*128);
    for (int idx = t; idx < 8192; idx += 256){
      int d = idx >> 6, i2 = idx & 63;
      ktd[idx] = f2bf(Ks[i2][d]);
    }
  }
}

// ---------- MFMA seq scan v3: 512 thr / 8 waves, dbuf S mirror, 2 barriers/step ----------
__global__ __launch_bounds__(512) void seq_kernel(
    const unsigned short* __restrict__ wneg_buf, const float* __restrict__ u_buf,
    const unsigned short* __restrict__ kt_buf, const unsigned short* __restrict__ qk_buf,
    const unsigned short* __restrict__ qbh, float* __restrict__ o_buf){
  int bid = blockIdx.x;
  int bh = bid & 15, cg = bid >> 4;
  int b = bh >> 3, hh = bh & 7;
  int cbase = hh*DK_;
  int t = threadIdx.x;
  int w = t >> 6, l = t & 63, g = l >> 4, lr = l & 15;
  int mt = w >> 1, nt = w & 1;
  int ct = w >> 2, dtp = (w & 3)*2;

  __shared__ __align__(16) unsigned short Wl[2][8192];
  __shared__ __align__(16) unsigned short Ql[2][8192];
  __shared__ __align__(16) unsigned short Ktl[2][8192];
  __shared__ __align__(16) unsigned short qkl[2][4096];
  __shared__ __align__(16) float  Ul[2][2048];
  __shared__ __align__(16) unsigned short Stl[2][32*136];
  __shared__ __align__(16) unsigned short vTl[32*72];

  f32x4 Sacc[2];
  Sacc[0] = (f32x4){0.f,0.f,0.f,0.f};
  Sacc[1] = (f32x4){0.f,0.f,0.f,0.f};

  for (int z=t; z<2*32*136; z+=512) ((unsigned short*)Stl)[z] = 0;

  size_t cid0 = (size_t)bh*NC_;
  const unsigned short* wb_  = wneg_buf + cid0*8192;
  const unsigned short* ktb_ = kt_buf  + cid0*8192;
  const unsigned short* qkb_ = qk_buf  + cid0*4096;
  const float*          ub_  = u_buf   + cid0*8192;
  const unsigned short* qb_  = qbh + (size_t)(b*L_)*D_ + cbase;

  int offW[2], offQ[2], offK[2];
  #pragma unroll
  for (int r=0;r<2;r++){
    int u = r*512 + t;
    int fm = u>>8, kq = (u>>6)&3, ll = u&63;
    offW[r] = (16*fm + (ll&15))*128 + kq*32 + (ll>>4)*8;
    offQ[r] = (16*fm + (ll&15))*D_  + kq*32 + (ll>>4)*8;
    int fn = u>>7, kqk = (u>>6)&1;
    offK[r] = (16*fn + (ll&15))*64 + kqk*32 + (ll>>4)*8;
  }
  int offQk, offU;
  {
    int u = t;
    int fm = u>>7, kq = (u>>6)&1, ll = u&63;
    offQk = (16*fm + (ll&15))*64 + kq*32 + (ll>>4)*8;
    offU  = (u>>3)*128 + cg*32 + (u&7)*4;
  }

  #define STAGE(BI, CI) do { \
    const unsigned short* wp  = wb_  + (size_t)(CI)*8192; \
    const unsigned short* kp  = ktb_ + (size_t)(CI)*8192; \
    const unsigned short* qkp = qkb_ + (size_t)(CI)*4096; \
    const float*          up  = ub_  + (size_t)(CI)*8192; \
    const unsigned short* qp  = qb_  + (size_t)(CI)*CS_*D_; \
    _Pragma("unroll") \
    for (int r=0;r<2;r++){ \
      gll16(wp + offW[r], &Wl[BI][(r*512+t)*8]); \
      gll16(qp + offQ[r], &Ql[BI][(r*512+t)*8]); \
      gll16(kp + offK[r], &Ktl[BI][(r*512+t)*8]); \
    } \
    gll16(qkp + offQk, &qkl[BI][t*8]); \
    gll16(up + offU, &Ul[BI][t*4]); \
  } while(0)

  STAGE(0, 0);
  asm volatile("s_waitcnt vmcnt(0) lgkmcnt(0)" ::: "memory");
  __builtin_amdgcn_s_barrier();
  __builtin_amdgcn_sched_barrier(0);

  int cur = 0;
  for (int ci=0; ci<NC_; ++ci){
    int cn = (ci+1 < NC_) ? ci+1 : ci;
    STAGE(cur^1, cn);

    // ---- phase B: v_new = U + (-W)@S_prev ----
    f32x4 accV;
    #pragma unroll
    for (int r=0;r<4;r++) accV[r] = Ul[cur][(16*mt + 4*g + r)*32 + 16*nt + lr];
    #pragma unroll
    for (int kq=0;kq<4;kq++){
      short8 a  = *(const short8*)&Wl[cur][(mt*4+kq)*512 + l*8];
      short8 b0 = *(const short8*)&Stl[cur][(16*nt + lr)*136 + kq*32 + g*8];
      accV = __builtin_amdgcn_mfma_f32_16x16x32_bf16(a, b0, accV, 0,0,0);
    }
    #pragma unroll
    for (int r=0;r<4;r++)
      vTl[(16*nt + lr)*72 + 16*mt + 4*g + r] = f2bf(accV[r]);
    asm volatile("s_waitcnt lgkmcnt(0)" ::: "memory");
    __builtin_amdgcn_s_barrier();
    __builtin_amdgcn_sched_barrier(0);

    // ---- phase CD: D (S update, regs) + C (o out); C reads Stl[cur], D writes Stl[cur^1] ----
    #pragma unroll
    for (int kq=0;kq<2;kq++){
      short8 aD = *(const short8*)&vTl[(16*ct + lr)*72 + kq*32 + g*8];
      short8 bD0 = *(const short8*)&Ktl[cur][((dtp+0)*2 + kq)*512 + l*8];
      short8 bD1 = *(const short8*)&Ktl[cur][((dtp+1)*2 + kq)*512 + l*8];
      Sacc[0] = __builtin_amdgcn_mfma_f32_16x16x32_bf16(aD, bD0, Sacc[0], 0,0,0);
      Sacc[1] = __builtin_amdgcn_mfma_f32_16x16x32_bf16(aD, bD1, Sacc[1], 0,0,0);
    }
    f32x4 accO = (f32x4){0.f,0.f,0.f,0.f};
    #pragma unroll
    for (int kq=0;kq<4;kq++){
      short8 a  = *(const short8*)&Ql[cur][(mt*4+kq)*512 + l*8];
      short8 b0 = *(const short8*)&Stl[cur][(16*nt + lr)*136 + kq*32 + g*8];
      accO = __builtin_amdgcn_mfma_f32_16x16x32_bf16(a, b0, accO, 0,0,0);
    }
    #pragma unroll
    for (int kq=0;kq<2;kq++){
      short8 a  = *(const short8*)&qkl[cur][(mt*2+kq)*512 + l*8];
      short8 b0 = *(const short8*)&vTl[(16*nt + lr)*72 + kq*32 + g*8];
      accO = __builtin_amdgcn_mfma_f32_16x16x32_bf16(a, b0, accO, 0,0,0);
    }
    #pragma unroll
    for (int j=0;j<2;j++){
      #pragma unroll
      for (int r=0;r<4;r++)
        Stl[cur^1][(16*ct + 4*g + r)*136 + 16*(dtp+j) + lr] = f2bf(Sacc[j][r]);
    }
    {
      int n0 = b*L_ + ci*CS_;
      #pragma unroll
      for (int r=0;r<4;r++)
        o_buf[(size_t)(n0 + 16*mt + 4*g + r)*D_ + cbase + cg*32 + 16*nt + lr] = accO[r];
    }
    asm volatile("s_waitcnt lgkmcnt(0)" ::: "memory");
    asm volatile("s_waitcnt vmcnt(4)" ::: "memory");
    __builtin_amdgcn_s_barrier();
    __builtin_amdgcn_sched_barrier(0);
    cur ^= 1;
  }
  #undef STAGE
}

// ---------- per-head RMSNorm over DV=128, bf16 out ----------
__global__ __launch_bounds__(256) void head_rmsnorm_kernel(const float* __restrict__ o,
    const float* __restrict__ w, unsigned short* __restrict__ out){
  int n = blockIdx.x, t = threadIdx.x;
  float4 v = ((const float4*)(o + (size_t)n*D_))[t];
  float ss = v.x*v.x+v.y*v.y+v.z*v.z+v.w*v.w;
  #pragma unroll
  for (int m=16;m>0;m>>=1) ss += __shfl_xor(ss, m, 64);
  float rs = rsqrtf(ss*(1.0f/DK_) + 1e-6f);
  float4 wv = ((const float4*)w)[t & 31];
  float4 u; u.x=v.x*rs*wv.x; u.y=v.y*rs*wv.y; u.z=v.z*rs*wv.z; u.w=v.w*rs*wv.w;
  ushort4 r4; r4.x=f2bf(u.x); r4.y=f2bf(u.y); r4.z=f2bf(u.z); r4.w=f2bf(u.w);
  ((ushort4*)(out + (size_t)n*D_))[t] = r4;
}

extern "C" void kernel_launch(void* const* d_in, const int* in_sizes, int n_in,
                              void* d_out, int out_size, void* d_ws, size_t ws_size,
                              hipStream_t stream){
  const float* x      = (const float*)d_in[0];
  const float* norm_w = (const float*)d_in[1];
  const float* Wq     = (const float*)d_in[2];
  const float* Wk     = (const float*)d_in[3];
  const float* Wv     = (const float*)d_in[4];
  const float* Wb     = (const float*)d_in[5];
  const float* conv_q = (const float*)d_in[6];
  const float* conv_k = (const float*)d_in[7];
  const float* conv_v = (const float*)d_in[8];
  const float* onw    = (const float*)d_in[9];
  const float* Wo     = (const float*)d_in[10];
  float* out = (float*)d_out;

  const size_t NB = (size_t)NR_*D_;           // 8,388,608 floats
  float* ws   = (float*)d_ws;
  float* h    = ws;                 // region free: [0,NB/2)=obb, [NB/2,NB)=qbh (both bf16)
  float* qkv  = ws + NB;            // fused [8192][3072] f32; later recurrence buffers
  float* qb   = ws + 4*NB;          // hb (bf16) aliases here until fused conv writes qb
  float* kb   = ws + 5*NB;
  float* vb   = ws + 6*NB;          // v f32 -> o f32 (seq output)
  float* betab= ws + 7*NB;          // 65536 floats
  unsigned short* wtq = (unsigned short*)(betab + 65536);  // 4 transposed weights contiguous
  unsigned short* wto = wtq + (size_t)3*D_*D_;
  unsigned short* hb  = (unsigned short*)qb;
  unsigned short* obb = (unsigned short*)h;
  unsigned short* qbh = (unsigned short*)(h + NB/2);
  unsigned short* wneg = (unsigned short*)qkv;             // 16MB
  unsigned short* ktb  = wneg + (size_t)8*1024*1024;       // 16MB
  unsigned short* qkbf = ktb  + (size_t)8*1024*1024;       // 8MB
  float*          ubuf = (float*)(qkbf + (size_t)4*1024*1024); // 32MB

  rmsnorm_beta_kernel<<<NR_, 256, 0, stream>>>(x, norm_w, Wb, hb, betab);
  transpose4_bf16_kernel<<<dim3(16,16,4), 256, 0, stream>>>(Wq, Wk, Wv, Wo, wtq);
  // fused QKV projection: N = 3072
  dim3 gq(3*D_/128, NR_/128);   // (24, 64)
  gemm_bf16<<<gq, 256, 0, stream>>>(hb, wtq, nullptr, qkv, 3*D_, D_);
  const float qscale = 0.08838834764831845f;  // DK^-0.5
  conv_silu_l2norm_kernel<<<NR_, 256, 0, stream>>>(qkv,      conv_q, qb, qbh, qscale, 3*D_);
  conv_silu_l2norm_kernel<<<NR_, 256, 0, stream>>>(qkv + D_, conv_k, kb, nullptr, 1.0f, 3*D_);
  conv_silu_kernel<<<(int)(NB/256), 256, 0, stream>>>(qkv + 2*D_, conv_v, vb, 3*D_);
  chunk_local_kernel<<<dim3(NC_, 16), 256, 0, stream>>>(qb, kb, vb, betab,
      wneg, ubuf, qkbf, ktb);
  seq_kernel<<<64, 512, 0, stream>>>(wneg, ubuf, ktb, qkbf, qbh, vb);
  head_rmsnorm_kernel<<<NR_, 256, 0, stream>>>(vb, onw, obb);
  dim3 gg(D_/128, NR_/128);
  gemm_bf16<<<gg, 256, 0, stream>>>(obb, wto, x, out, D_, D_);
  (void)in_sizes; (void)n_in; (void)out_size; (void)ws_size;
}